// Round 1
// 778.157 us; speedup vs baseline: 1.2605x; 1.2605x over previous
//
#include <hip/hip_runtime.h>
#include <hip/hip_bf16.h>
#include <math.h>

#define H 128
#define RS 136    // LDS row stride in shorts (128 + 8 pad; keeps ds_read_b128 16B-aligned)
#define BSH 9     // bin shift: 512 nodes per bin
#define BINW 512
#define BCAP 11264  // max edges/bin for LDS sort (expected max ~10.6k at deg-20, 512 nodes)
#define KEDGE 4096  // edges per partition block
#define EPT 16      // edges per thread (KEDGE/256)
#define MAXBINS 1024

typedef __attribute__((ext_vector_type(8))) short short8;
typedef __attribute__((ext_vector_type(4))) short short4v;
typedef __attribute__((ext_vector_type(4))) float f32x4;
typedef __attribute__((ext_vector_type(2))) _Float16 half2v;
typedef __attribute__((ext_vector_type(4))) _Float16 half4v;
typedef __attribute__((ext_vector_type(8))) _Float16 half8v;

// fp32 -> bf16 (RNE); values here are finite (no NaN handling needed)
__device__ __forceinline__ short f2bf(float f) {
    unsigned u = __float_as_uint(f);
    u += 0x7fff + ((u >> 16) & 1);
    return (short)(u >> 16);
}
__device__ __forceinline__ float bf2f(short h) {
    return __uint_as_float(((unsigned)(unsigned short)h) << 16);
}

// ---------------- CSR build ----------------
// Node space concatenated: [NP(isa) | NG(rel) | NP(rev)].

__global__ __launch_bounds__(256) void count_all_kernel(
    const int* __restrict__ e0, int E0, const int* __restrict__ e1, int E1,
    const int* __restrict__ e2, int E2, int* __restrict__ cnt, int NPn, int NGn) {
    int g = blockIdx.x * 256 + threadIdx.x;
    const int* ed; int E, lo, base;
    if (g < E0) { ed = e0; E = E0; lo = g; base = 0; }
    else if (g < E0 + E1) { ed = e1; E = E1; lo = g - E0; base = NPn; }
    else if (g < E0 + E1 + E2) { ed = e2; E = E2; lo = g - E0 - E1; base = NPn + NGn; }
    else return;
    atomicAdd(&cnt[base + ed[E + lo]], 1);
}

__global__ __launch_bounds__(256) void scan_pass1(const int* __restrict__ cnt, int n,
                                                  int* __restrict__ partial) {
    int base = blockIdx.x * 1024 + threadIdx.x * 4;
    int s = 0;
    if (base + 3 < n) {
        int4 v = *(const int4*)&cnt[base];
        s = v.x + v.y + v.z + v.w;
    } else {
        for (int i = 0; i < 4; ++i) if (base + i < n) s += cnt[base + i];
    }
    __shared__ int red[256];
    red[threadIdx.x] = s;
    __syncthreads();
    for (int off = 128; off; off >>= 1) {
        if (threadIdx.x < off) red[threadIdx.x] += red[threadIdx.x + off];
        __syncthreads();
    }
    if (threadIdx.x == 0) partial[blockIdx.x] = red[0];
}

__global__ __launch_bounds__(1024) void scan_pass2(int* __restrict__ partial, int nb,
                                                   int* __restrict__ total_out) {
    __shared__ int sh[1024];
    int t = threadIdx.x;
    int v = (t < nb) ? partial[t] : 0;
    sh[t] = v;
    __syncthreads();
    for (int off = 1; off < 1024; off <<= 1) {
        int u = (t >= off) ? sh[t - off] : 0;
        __syncthreads();
        sh[t] += u;
        __syncthreads();
    }
    if (t < nb) partial[t] = sh[t] - v;   // exclusive
    if (t == 1023) *total_out = sh[1023];
}

__global__ __launch_bounds__(256) void scan_pass3(const int* __restrict__ cnt, int n,
                                                  const int* __restrict__ partial,
                                                  int* __restrict__ rowptr) {
    int t = threadIdx.x;
    int base = blockIdx.x * 1024 + t * 4;
    int v[4];
    int s = 0;
    for (int i = 0; i < 4; ++i) {
        v[i] = (base + i < n) ? cnt[base + i] : 0;
        s += v[i];
    }
    __shared__ int sh[256];
    sh[t] = s;
    __syncthreads();
    for (int off = 1; off < 256; off <<= 1) {
        int u = (t >= off) ? sh[t - off] : 0;
        __syncthreads();
        sh[t] += u;
        __syncthreads();
    }
    int run = partial[blockIdx.x] + sh[t] - s;
    for (int i = 0; i < 4; ++i) {
        int idx = base + i;
        if (idx < n) {
            rowptr[idx] = run;
            run += v[i];
        }
    }
}

// bin cursor init: bin b's frontier = rowptr[b*BINW]; PADDED to 1 counter per 64B line.
__global__ __launch_bounds__(256) void bin_init_kernel(const int* __restrict__ rowptr,
                                                       int* __restrict__ bin_cur,
                                                       int nbins, int n_tot) {
    int b = blockIdx.x * 256 + threadIdx.x;
    if (b < nbins) {
        int node = b << BSH;
        if (node > n_tot) node = n_tot;
        bin_cur[b * 16] = rowptr[node];
    }
}

// pass A: block-aggregated partition. Per block: LDS histogram over bins, ONE global
// atomicAdd per touched bin (reserve a contiguous run), then scatter from registers via
// LDS run-cursors.
// payload: src | (local_dst << 16)  (src < 2^16, local_dst < 512 -> bits 16..24)
__global__ __launch_bounds__(256) void bin_scatter_kernel(
    const int* __restrict__ e0, int E0, const int* __restrict__ e1, int E1,
    const int* __restrict__ e2, int E2, int* __restrict__ bin_cur,
    int* __restrict__ temp, int NPn, int NGn, int nbins, int E_tot) {
    __shared__ int hist[MAXBINS];
    __shared__ int cur[MAXBINS];
    int t = threadIdx.x;
    for (int i = t; i < nbins; i += 256) hist[i] = 0;
    __syncthreads();
    int vals[EPT], bins[EPT];
    int base_e = blockIdx.x * KEDGE;
#pragma unroll
    for (int j = 0; j < EPT; ++j) {
        int g = base_e + j * 256 + t;      // coalesced within each j-step
        int b = -1, v = 0;
        if (g < E_tot) {
            const int* ed; int E, lo, nbase;
            if (g < E0) { ed = e0; E = E0; lo = g; nbase = 0; }
            else if (g < E0 + E1) { ed = e1; E = E1; lo = g - E0; nbase = NPn; }
            else { ed = e2; E = E2; lo = g - E0 - E1; nbase = NPn + NGn; }
            int src = ed[lo];
            int gdst = nbase + ed[E + lo];
            v = src | ((gdst & (BINW - 1)) << 16);
            b = gdst >> BSH;
            atomicAdd(&hist[b], 1);        // LDS atomic
        }
        vals[j] = v;
        bins[j] = b;
    }
    __syncthreads();
    for (int i = t; i < nbins; i += 256) {
        int h = hist[i];
        cur[i] = h ? atomicAdd(&bin_cur[i * 16], h) : 0;   // reserve run; cur = global base
    }
    __syncthreads();
#pragma unroll
    for (int j = 0; j < EPT; ++j) {
        if (bins[j] >= 0) {
            int p = atomicAdd(&cur[bins[j]], 1);           // LDS atomic -> global slot
            temp[p] = vals[j];
        }
    }
}

// pass B: per-bin LDS counting sort; col written fully coalesced.
__global__ __launch_bounds__(256) void bin_sort_kernel(
    const int* __restrict__ rowptr, const int* __restrict__ temp,
    int* __restrict__ col, int n_tot) {
    __shared__ int srt[BCAP];
    __shared__ int cur[BINW];
    __shared__ int rp[BINW + 1];
    int b = blockIdx.x;
    int start = b << BSH;
    int nodes = n_tot - start; if (nodes > BINW) nodes = BINW;
    int t = threadIdx.x;
    for (int i = t; i <= nodes; i += 256) rp[i] = rowptr[start + i];
    __syncthreads();
    int base = rp[0];
    int count = rp[nodes] - base;
    for (int i = t; i < nodes; i += 256) cur[i] = rp[i] - base;  // local exclusive starts
    __syncthreads();
    if (count <= BCAP) {
        for (int i = t; i < count; i += 256) {
            int v = temp[base + i];
            int p = atomicAdd(&cur[(v >> 16) & (BINW - 1)], 1);
            srt[p] = v & 0xFFFF;
        }
        __syncthreads();
        for (int i = t; i < count; i += 256) col[base + i] = srt[i];
    } else {  // fallback (not expected): direct global scatter
        for (int i = t; i < count; i += 256) {
            int v = temp[base + i];
            int p = atomicAdd(&cur[(v >> 16) & (BINW - 1)], 1);
            col[base + p] = v & 0xFFFF;
        }
    }
}

// ---------------- W pack: fp32 [k][n] -> MFMA B-fragment order, split bf16 hi/lo ----------------
// 15 matrices (5 per layer: Wl_isa, Wl_rev, Wsum=Wr_isa+Wr_rev, Wl_rel, Wr_rel).
// B-operand layout: n = ct*16 + (lane&15), k = kc*32 + (lane>>4)*8 + j.

struct WSrc { const float* a[15]; const float* b[15]; };

__global__ __launch_bounds__(256) void pack_w_kernel(WSrc src, short* __restrict__ whi,
                                                     short* __restrict__ wlo) {
    int idx = blockIdx.x * 256 + threadIdx.x;   // (mat, kc, ct, lane)
    if (idx >= 15 * 4 * 8 * 64) return;
    int lane = idx & 63;
    int ct = (idx >> 6) & 7;
    int kc = (idx >> 9) & 3;
    int mat = idx >> 11;
    const float* A = src.a[mat];
    const float* Bp = src.b[mat];
    int n = ct * 16 + (lane & 15);
    int kbase = kc * 32 + (lane >> 4) * 8;
    size_t o = (size_t)idx * 8;
    for (int j = 0; j < 8; ++j) {
        float v = A[(size_t)(kbase + j) * H + n];
        if (Bp) v += Bp[(size_t)(kbase + j) * H + n];
        short h = f2bf(v);
        whi[o + j] = h;
        wlo[o + j] = f2bf(v - bf2f(h));
    }
}

// ---------------- fp32 -> fp16 mirror convert (layer-0 inputs) ----------------

__global__ __launch_bounds__(256) void cvt16_kernel(const float* __restrict__ x,
                                                    _Float16* __restrict__ y, int n4) {
    int i = blockIdx.x * 256 + threadIdx.x;
    if (i >= n4) return;
    f32x4 v = *(const f32x4*)&x[(size_t)i * 4];
    half4v h;
#pragma unroll
    for (int k = 0; k < 4; ++k) h[k] = (_Float16)v[k];
    *(half4v*)&y[(size_t)i * 4] = h;
}

// ---------------- merged per-layer segment mean (fp16 gather, fp32 accumulate) ----------------
// Wave w < NP: isa-mean(xp)->M1[w] AND rev-mean(xg)->M2[w]. Wave in [NP,NP+NG): rel-mean(xp)->M3.
// Gathers read the fp16 mirror (256 B/row instead of 512 B) -> halves the EA-path traffic
// that bounds this kernel. Accumulation and M outputs stay fp32.

__device__ __forceinline__ float2 seg_mean16(const _Float16* __restrict__ x,
                                             const int* __restrict__ col,
                                             int beg, int end, int off) {
    float ax[8], ay[8];
#pragma unroll
    for (int i = 0; i < 8; ++i) { ax[i] = 0.f; ay[i] = 0.f; }
    int e = beg;
    for (; e + 7 < end; e += 8) {
        int s[8];
#pragma unroll
        for (int i = 0; i < 8; ++i) s[i] = col[e + i];
#pragma unroll
        for (int i = 0; i < 8; ++i) {
            half2v v = *(const half2v*)&x[(size_t)s[i] * H + off];
            ax[i] += (float)v[0]; ay[i] += (float)v[1];
        }
    }
    for (; e < end; ++e) {
        half2v v = *(const half2v*)&x[(size_t)col[e] * H + off];
        ax[0] += (float)v[0]; ay[0] += (float)v[1];
    }
    float sx = ((ax[0] + ax[1]) + (ax[2] + ax[3])) + ((ax[4] + ax[5]) + (ax[6] + ax[7]));
    float sy = ((ay[0] + ay[1]) + (ay[2] + ay[3])) + ((ay[4] + ay[5]) + (ay[6] + ay[7]));
    int c = end - beg; if (c < 1) c = 1;
    float inv = 1.0f / (float)c;
    return (float2){sx * inv, sy * inv};
}

__global__ __launch_bounds__(256) void agg_all_kernel(
    const _Float16* __restrict__ xp, const _Float16* __restrict__ xg,
    const int* __restrict__ rowptr, const int* __restrict__ col,
    float* __restrict__ M1, float* __restrict__ M2, float* __restrict__ M3,
    int NPn, int NGn) {
    int w = (blockIdx.x << 2) + (threadIdx.x >> 6);
    int lane = threadIdx.x & 63;
    int off = lane * 2;
    if (w < NPn) {
        float2 r1 = seg_mean16(xp, col, rowptr[w], rowptr[w + 1], off);
        *(float2*)&M1[(size_t)w * H + off] = r1;
        int b = NPn + NGn + w;
        float2 r2 = seg_mean16(xg, col, rowptr[b], rowptr[b + 1], off);
        *(float2*)&M2[(size_t)w * H + off] = r2;
    } else if (w < NPn + NGn) {
        float2 r3 = seg_mean16(xp, col, rowptr[w], rowptr[w + 1], off);
        *(float2*)&M3[(size_t)(w - NPn) * H + off] = r3;
    }
}

// ---------------- split-bf16 MFMA GEMM, double-buffered B prefetch (proven R6) ----------------
// Epilogue now additionally stores an fp16 mirror of the output (consumed by the next
// layer's agg gather and by the decoder).

template <int NIN>
__global__ __launch_bounds__(256, 3) void gemm_mfma(
    const float* __restrict__ A0, const float* __restrict__ A1, const float* __restrict__ A2,
    const short* __restrict__ whi, const short* __restrict__ wlo,
    int mat0, int mat1, int mat2,
    const float* __restrict__ b0, const float* __restrict__ b1,
    float* __restrict__ out, _Float16* __restrict__ out16, int n_rows, int relu) {
    __shared__ short Ahi[64 * RS];
    __shared__ short Alo[64 * RS];
    const int tid = threadIdx.x;
    const int lane = tid & 63;
    const int wave = tid >> 6;
    const int r0 = blockIdx.x * 64;
    const int ct0 = wave * 2;
    const int m16 = lane & 15;
    const int acol = (lane >> 4) * 8;

    f32x4 acc[4][2];
#pragma unroll
    for (int mt = 0; mt < 4; ++mt)
#pragma unroll
        for (int c = 0; c < 2; ++c) acc[mt][c] = (f32x4){0.f, 0.f, 0.f, 0.f};

    const float* Aarr[3] = {A0, A1, A2};
    const int marr[3] = {mat0, mat1, mat2};

    short8 bh[2][2], bl[2][2];
    {
        const short* wh = whi + (size_t)marr[0] * (H * H);
        const short* wl = wlo + (size_t)marr[0] * (H * H);
        size_t f0 = ((size_t)ct0 * 64 + lane) * 8;
        bh[0][0] = *(const short8*)&wh[f0];
        bh[0][1] = *(const short8*)&wh[f0 + 512];
        bl[0][0] = *(const short8*)&wl[f0];
        bl[0][1] = *(const short8*)&wl[f0 + 512];
    }

#pragma unroll
    for (int m = 0; m < NIN; ++m) {
        const float* __restrict__ A = Aarr[m];
        const short* __restrict__ wh = whi + (size_t)marr[m] * (H * H);
        const short* __restrict__ wl = wlo + (size_t)marr[m] * (H * H);
        __syncthreads();
#pragma unroll
        for (int i = 0; i < 8; ++i) {
            int f = tid + i * 256;
            int row = f >> 5;
            int c4 = (f & 31) * 4;
            int gr = r0 + row;
            if (gr >= n_rows) gr = n_rows - 1;
            float4 v = *(const float4*)&A[(size_t)gr * H + c4];
            short h0 = f2bf(v.x), h1 = f2bf(v.y), h2 = f2bf(v.z), h3 = f2bf(v.w);
            *(short4v*)&Ahi[row * RS + c4] = (short4v){h0, h1, h2, h3};
            *(short4v*)&Alo[row * RS + c4] =
                (short4v){f2bf(v.x - bf2f(h0)), f2bf(v.y - bf2f(h1)),
                          f2bf(v.z - bf2f(h2)), f2bf(v.w - bf2f(h3))};
        }
        __syncthreads();
#pragma unroll
        for (int kc = 0; kc < 4; ++kc) {
            if (kc < 3) {
                int nb = (kc + 1) & 1;
                size_t f = ((size_t)((kc + 1) * 8 + ct0) * 64 + lane) * 8;
                bh[nb][0] = *(const short8*)&wh[f];
                bh[nb][1] = *(const short8*)&wh[f + 512];
                bl[nb][0] = *(const short8*)&wl[f];
                bl[nb][1] = *(const short8*)&wl[f + 512];
            } else if (m + 1 < NIN) {
                const short* wh2 = whi + (size_t)marr[m + 1] * (H * H);
                const short* wl2 = wlo + (size_t)marr[m + 1] * (H * H);
                size_t f = ((size_t)ct0 * 64 + lane) * 8;
                bh[0][0] = *(const short8*)&wh2[f];
                bh[0][1] = *(const short8*)&wh2[f + 512];
                bl[0][0] = *(const short8*)&wl2[f];
                bl[0][1] = *(const short8*)&wl2[f + 512];
            }
            int cb = kc & 1;
#pragma unroll
            for (int mt = 0; mt < 4; ++mt) {
                short8 ah = *(const short8*)&Ahi[(mt * 16 + m16) * RS + kc * 32 + acol];
                short8 al = *(const short8*)&Alo[(mt * 16 + m16) * RS + kc * 32 + acol];
#pragma unroll
                for (int c = 0; c < 2; ++c) {
                    acc[mt][c] = __builtin_amdgcn_mfma_f32_16x16x32_bf16(ah, bh[cb][c], acc[mt][c], 0, 0, 0);
                    acc[mt][c] = __builtin_amdgcn_mfma_f32_16x16x32_bf16(al, bh[cb][c], acc[mt][c], 0, 0, 0);
                    acc[mt][c] = __builtin_amdgcn_mfma_f32_16x16x32_bf16(ah, bl[cb][c], acc[mt][c], 0, 0, 0);
                }
            }
        }
    }

    const int rquad = (lane >> 4) * 4;
    const int ncol = lane & 15;
#pragma unroll
    for (int c = 0; c < 2; ++c) {
        int n = (ct0 + c) * 16 + ncol;
        float bs = b0[n];
        if (b1) bs += b1[n];
#pragma unroll
        for (int mt = 0; mt < 4; ++mt) {
#pragma unroll
            for (int reg = 0; reg < 4; ++reg) {
                int gr = r0 + mt * 16 + rquad + reg;
                if (gr < n_rows) {
                    float v = acc[mt][c][reg] + bs;
                    if (relu) v = v > 0.f ? v : 0.01f * v;
                    out[(size_t)gr * H + n] = v;
                    out16[(size_t)gr * H + n] = (_Float16)v;
                }
            }
        }
    }
}

// ---------------- edge decoder: sigmoid(dot(xp[i], xg[j])) on fp16 mirrors ----------------

__global__ __launch_bounds__(256) void scores_kernel(const _Float16* __restrict__ xp,
                                                     const _Float16* __restrict__ xg,
                                                     const int* __restrict__ eli, int E,
                                                     float* __restrict__ out) {
    int lane16 = threadIdx.x & 15;
    int sub = threadIdx.x >> 4;     // 16 edges per block
    int e = blockIdx.x * 16 + sub;
    if (e >= E) return;
    int ip = eli[e];
    int ig = eli[E + e];
    half8v a = *(const half8v*)&xp[(size_t)ip * H + lane16 * 8];
    half8v b = *(const half8v*)&xg[(size_t)ig * H + lane16 * 8];
    float s = 0.f;
#pragma unroll
    for (int k = 0; k < 8; ++k) s += (float)a[k] * (float)b[k];
#pragma unroll
    for (int off = 8; off; off >>= 1) s += __shfl_xor(s, off, 16);
    if (lane16 == 0) out[e] = 1.0f / (1.0f + expf(-s));
}

// ---------------- host ----------------

extern "C" void kernel_launch(void* const* d_in, const int* in_sizes, int n_in,
                              void* d_out, int out_size, void* d_ws, size_t ws_size,
                              hipStream_t stream) {
    const float* x_pheno = (const float*)d_in[0];
    const float* x_gene  = (const float*)d_in[1];
    const float* Wl_isa  = (const float*)d_in[2];
    const float* bl_isa  = (const float*)d_in[3];
    const float* Wr_isa  = (const float*)d_in[4];
    const float* Wl_rel  = (const float*)d_in[5];
    const float* bl_rel  = (const float*)d_in[6];
    const float* Wr_rel  = (const float*)d_in[7];
    const float* Wl_rev  = (const float*)d_in[8];
    const float* bl_rev  = (const float*)d_in[9];
    const float* Wr_rev  = (const float*)d_in[10];
    const int* e_isa = (const int*)d_in[11];
    const int* e_rel = (const int*)d_in[12];
    const int* e_rev = (const int*)d_in[13];
    const int* e_lbl = (const int*)d_in[14];
    const int E_isa = in_sizes[11] / 2;
    const int E_rel = in_sizes[12] / 2;
    const int E_rev = in_sizes[13] / 2;
    const int E_lbl = in_sizes[14] / 2;
    const int NP = in_sizes[0] / H;
    const int NG = in_sizes[1] / H;
    const int NMAX = NP > NG ? NP : NG;
    const int n_tot = NP + NG + NP;
    const int E_tot = E_isa + E_rel + E_rev;
    const int nb = (n_tot + 1023) / 1024;
    const int nbins = (n_tot + BINW - 1) / BINW;

    char* ws = (char*)d_ws;
    auto alloc = [&](size_t bytes) -> char* {
        char* p = ws;
        ws += (bytes + 255) & ~(size_t)255;
        return p;
    };
    float* B[5];
    for (int i = 0; i < 5; ++i) B[i] = (float*)alloc((size_t)NMAX * H * sizeof(float));
    int* cnt     = (int*)alloc((size_t)n_tot * 4);
    int* rowptr  = (int*)alloc((size_t)(n_tot + 1) * 4);
    int* col     = (int*)alloc((size_t)E_tot * 4);
    int* temp    = (int*)alloc((size_t)E_tot * 4);
    int* bin_cur = (int*)alloc((size_t)nbins * 16 * 4);   // 64B-strided counters
    int* partial = (int*)alloc((size_t)1024 * 4);
    short* whi = (short*)alloc((size_t)15 * H * H * sizeof(short));
    short* wlo = (short*)alloc((size_t)15 * H * H * sizeof(short));
    _Float16* xp16 = (_Float16*)alloc((size_t)NP * H * sizeof(_Float16));
    _Float16* xg16 = (_Float16*)alloc((size_t)NG * H * sizeof(_Float16));

    // ---- CSR build (every call; ws is re-poisoned by the harness) ----
    hipMemsetAsync(cnt, 0, (size_t)n_tot * 4, stream);
    count_all_kernel<<<(E_tot + 255) / 256, 256, 0, stream>>>(
        e_isa, E_isa, e_rel, E_rel, e_rev, E_rev, cnt, NP, NG);
    scan_pass1<<<nb, 256, 0, stream>>>(cnt, n_tot, partial);
    scan_pass2<<<1, 1024, 0, stream>>>(partial, nb, &rowptr[n_tot]);
    scan_pass3<<<nb, 256, 0, stream>>>(cnt, n_tot, partial, rowptr);
    bin_init_kernel<<<(nbins + 255) / 256, 256, 0, stream>>>(rowptr, bin_cur, nbins, n_tot);
    bin_scatter_kernel<<<(E_tot + KEDGE - 1) / KEDGE, 256, 0, stream>>>(
        e_isa, E_isa, e_rel, E_rel, e_rev, E_rev, bin_cur, temp, NP, NG, nbins, E_tot);
    bin_sort_kernel<<<nbins, 256, 0, stream>>>(rowptr, temp, col, n_tot);

    // ---- W pack: per layer slots {Wl_isa, Wl_rev, Wsum=Wr_isa+Wr_rev, Wl_rel, Wr_rel} ----
    WSrc src;
    for (int l = 0; l < 3; ++l) {
        src.a[l * 5 + 0] = Wl_isa + (size_t)l * H * H;  src.b[l * 5 + 0] = nullptr;
        src.a[l * 5 + 1] = Wl_rev + (size_t)l * H * H;  src.b[l * 5 + 1] = nullptr;
        src.a[l * 5 + 2] = Wr_isa + (size_t)l * H * H;  src.b[l * 5 + 2] = Wr_rev + (size_t)l * H * H;
        src.a[l * 5 + 3] = Wl_rel + (size_t)l * H * H;  src.b[l * 5 + 3] = nullptr;
        src.a[l * 5 + 4] = Wr_rel + (size_t)l * H * H;  src.b[l * 5 + 4] = nullptr;
    }
    pack_w_kernel<<<(15 * 4 * 8 * 64 + 255) / 256, 256, 0, stream>>>(src, whi, wlo);

    // ---- layer-0 fp16 mirrors of the inputs ----
    cvt16_kernel<<<(NP * H / 4 + 255) / 256, 256, 0, stream>>>(x_pheno, xp16, NP * H / 4);
    cvt16_kernel<<<(NG * H / 4 + 255) / 256, 256, 0, stream>>>(x_gene, xg16, NG * H / 4);

    // ---- 3 layers ----
    // buffers: layer0 M1=B0 M2=B1 M3=B2; layer1 M1=B3 M2=B1 M3=B4; layer2 M1=B0 M2=B1 M3=B2
    // Per layer: agg reads the mirrors (written by the previous layer), THEN the GEMMs
    // overwrite the mirrors in place — safe under stream ordering.
    int mi[3] = {0, 3, 0}, mv[3] = {1, 1, 1}, mr[3] = {2, 4, 2};
    const float* xp = x_pheno;
    const float* xg = x_gene;
    for (int l = 0; l < 3; ++l) {
        float* M1 = B[mi[l]];
        float* M2 = B[mv[l]];
        float* M3 = B[mr[l]];
        agg_all_kernel<<<(NP + NG + 3) / 4, 256, 0, stream>>>(
            xp16, xg16, rowptr, col, M1, M2, M3, NP, NG);
        int relu = (l < 2) ? 1 : 0;
        const float* bli = bl_isa + (size_t)l * H;
        const float* blv = bl_rev + (size_t)l * H;
        const float* blr = bl_rel + (size_t)l * H;
        // new_p = M1@Wl_isa + M2@Wl_rev + xp@(Wr_isa+Wr_rev) + bl_isa + bl_rev -> M1 (in-place)
        gemm_mfma<3><<<(NP + 63) / 64, 256, 0, stream>>>(
            M1, M2, xp, whi, wlo, l * 5 + 0, l * 5 + 1, l * 5 + 2, bli, blv, M1, xp16, NP, relu);
        // new_g = M3@Wl_rel + xg@Wr_rel + bl_rel -> M3 (in-place)
        gemm_mfma<2><<<(NG + 63) / 64, 256, 0, stream>>>(
            M3, xg, nullptr, whi, wlo, l * 5 + 3, l * 5 + 4, 0, blr, nullptr, M3, xg16, NG, relu);
        xp = M1;
        xg = M3;
    }

    // ---- decoder (reads final-layer fp16 mirrors) ----
    scores_kernel<<<(E_lbl + 15) / 16, 256, 0, stream>>>(xp16, xg16, e_lbl, E_lbl, (float*)d_out);
}

// Round 3
// 761.404 us; speedup vs baseline: 1.2882x; 1.0220x over previous
//
#include <hip/hip_runtime.h>
#include <hip/hip_bf16.h>
#include <math.h>

#define H 128
#define RS 136    // LDS row stride in shorts (128 + 8 pad; keeps ds_read_b128 16B-aligned)
#define BSH 9     // bin shift: 512 nodes per bin
#define BINW 512
#define BCAP 11264  // max edges/bin for LDS sort (expected max ~10.6k at deg-20, 512 nodes)
#define KEDGE 4096  // edges per partition block
#define EPT 16      // edges per thread (KEDGE/256)
#define MAXBINS 1024

typedef __attribute__((ext_vector_type(8))) short short8;
typedef __attribute__((ext_vector_type(4))) short short4v;
typedef __attribute__((ext_vector_type(4))) float f32x4;
typedef __attribute__((ext_vector_type(2))) _Float16 half2v;
typedef __attribute__((ext_vector_type(4))) _Float16 half4v;
typedef __attribute__((ext_vector_type(8))) _Float16 half8v;

// fp32 -> bf16 (RNE); values here are finite (no NaN handling needed)
__device__ __forceinline__ short f2bf(float f) {
    unsigned u = __float_as_uint(f);
    u += 0x7fff + ((u >> 16) & 1);
    return (short)(u >> 16);
}
__device__ __forceinline__ float bf2f(short h) {
    return __uint_as_float(((unsigned)(unsigned short)h) << 16);
}

// ---------------- CSR build ----------------
// Node space concatenated: [NP(isa) | NG(rel) | NP(rev)].

__global__ __launch_bounds__(256) void count_all_kernel(
    const int* __restrict__ e0, int E0, const int* __restrict__ e1, int E1,
    const int* __restrict__ e2, int E2, int* __restrict__ cnt, int NPn, int NGn) {
    int g = blockIdx.x * 256 + threadIdx.x;
    const int* ed; int E, lo, base;
    if (g < E0) { ed = e0; E = E0; lo = g; base = 0; }
    else if (g < E0 + E1) { ed = e1; E = E1; lo = g - E0; base = NPn; }
    else if (g < E0 + E1 + E2) { ed = e2; E = E2; lo = g - E0 - E1; base = NPn + NGn; }
    else return;
    atomicAdd(&cnt[base + ed[E + lo]], 1);
}

__global__ __launch_bounds__(256) void scan_pass1(const int* __restrict__ cnt, int n,
                                                  int* __restrict__ partial) {
    int base = blockIdx.x * 1024 + threadIdx.x * 4;
    int s = 0;
    if (base + 3 < n) {
        int4 v = *(const int4*)&cnt[base];
        s = v.x + v.y + v.z + v.w;
    } else {
        for (int i = 0; i < 4; ++i) if (base + i < n) s += cnt[base + i];
    }
    __shared__ int red[256];
    red[threadIdx.x] = s;
    __syncthreads();
    for (int off = 128; off; off >>= 1) {
        if (threadIdx.x < off) red[threadIdx.x] += red[threadIdx.x + off];
        __syncthreads();
    }
    if (threadIdx.x == 0) partial[blockIdx.x] = red[0];
}

__global__ __launch_bounds__(1024) void scan_pass2(int* __restrict__ partial, int nb,
                                                   int* __restrict__ total_out) {
    __shared__ int sh[1024];
    int t = threadIdx.x;
    int v = (t < nb) ? partial[t] : 0;
    sh[t] = v;
    __syncthreads();
    for (int off = 1; off < 1024; off <<= 1) {
        int u = (t >= off) ? sh[t - off] : 0;
        __syncthreads();
        sh[t] += u;
        __syncthreads();
    }
    if (t < nb) partial[t] = sh[t] - v;   // exclusive
    if (t == 1023) *total_out = sh[1023];
}

__global__ __launch_bounds__(256) void scan_pass3(const int* __restrict__ cnt, int n,
                                                  const int* __restrict__ partial,
                                                  int* __restrict__ rowptr) {
    int t = threadIdx.x;
    int base = blockIdx.x * 1024 + t * 4;
    int v[4];
    int s = 0;
    for (int i = 0; i < 4; ++i) {
        v[i] = (base + i < n) ? cnt[base + i] : 0;
        s += v[i];
    }
    __shared__ int sh[256];
    sh[t] = s;
    __syncthreads();
    for (int off = 1; off < 256; off <<= 1) {
        int u = (t >= off) ? sh[t - off] : 0;
        __syncthreads();
        sh[t] += u;
        __syncthreads();
    }
    int run = partial[blockIdx.x] + sh[t] - s;
    for (int i = 0; i < 4; ++i) {
        int idx = base + i;
        if (idx < n) {
            rowptr[idx] = run;
            run += v[i];
        }
    }
}

// bin cursor init: bin b's frontier = rowptr[b*BINW]; PADDED to 1 counter per 64B line.
__global__ __launch_bounds__(256) void bin_init_kernel(const int* __restrict__ rowptr,
                                                       int* __restrict__ bin_cur,
                                                       int nbins, int n_tot) {
    int b = blockIdx.x * 256 + threadIdx.x;
    if (b < nbins) {
        int node = b << BSH;
        if (node > n_tot) node = n_tot;
        bin_cur[b * 16] = rowptr[node];
    }
}

// pass A: block-aggregated partition. Per block: LDS histogram over bins, ONE global
// atomicAdd per touched bin (reserve a contiguous run), then scatter from registers via
// LDS run-cursors.
// payload: src | (local_dst << 16)  (src < 2^16, local_dst < 512 -> bits 16..24)
__global__ __launch_bounds__(256) void bin_scatter_kernel(
    const int* __restrict__ e0, int E0, const int* __restrict__ e1, int E1,
    const int* __restrict__ e2, int E2, int* __restrict__ bin_cur,
    int* __restrict__ temp, int NPn, int NGn, int nbins, int E_tot) {
    __shared__ int hist[MAXBINS];
    __shared__ int cur[MAXBINS];
    int t = threadIdx.x;
    for (int i = t; i < nbins; i += 256) hist[i] = 0;
    __syncthreads();
    int vals[EPT], bins[EPT];
    int base_e = blockIdx.x * KEDGE;
#pragma unroll
    for (int j = 0; j < EPT; ++j) {
        int g = base_e + j * 256 + t;      // coalesced within each j-step
        int b = -1, v = 0;
        if (g < E_tot) {
            const int* ed; int E, lo, nbase;
            if (g < E0) { ed = e0; E = E0; lo = g; nbase = 0; }
            else if (g < E0 + E1) { ed = e1; E = E1; lo = g - E0; nbase = NPn; }
            else { ed = e2; E = E2; lo = g - E0 - E1; nbase = NPn + NGn; }
            int src = ed[lo];
            int gdst = nbase + ed[E + lo];
            v = src | ((gdst & (BINW - 1)) << 16);
            b = gdst >> BSH;
            atomicAdd(&hist[b], 1);        // LDS atomic
        }
        vals[j] = v;
        bins[j] = b;
    }
    __syncthreads();
    for (int i = t; i < nbins; i += 256) {
        int h = hist[i];
        cur[i] = h ? atomicAdd(&bin_cur[i * 16], h) : 0;   // reserve run; cur = global base
    }
    __syncthreads();
#pragma unroll
    for (int j = 0; j < EPT; ++j) {
        if (bins[j] >= 0) {
            int p = atomicAdd(&cur[bins[j]], 1);           // LDS atomic -> global slot
            temp[p] = vals[j];
        }
    }
}

// pass B: per-bin LDS counting sort; col written fully coalesced.
__global__ __launch_bounds__(256) void bin_sort_kernel(
    const int* __restrict__ rowptr, const int* __restrict__ temp,
    int* __restrict__ col, int n_tot) {
    __shared__ int srt[BCAP];
    __shared__ int cur[BINW];
    __shared__ int rp[BINW + 1];
    int b = blockIdx.x;
    int start = b << BSH;
    int nodes = n_tot - start; if (nodes > BINW) nodes = BINW;
    int t = threadIdx.x;
    for (int i = t; i <= nodes; i += 256) rp[i] = rowptr[start + i];
    __syncthreads();
    int base = rp[0];
    int count = rp[nodes] - base;
    for (int i = t; i < nodes; i += 256) cur[i] = rp[i] - base;  // local exclusive starts
    __syncthreads();
    if (count <= BCAP) {
        for (int i = t; i < count; i += 256) {
            int v = temp[base + i];
            int p = atomicAdd(&cur[(v >> 16) & (BINW - 1)], 1);
            srt[p] = v & 0xFFFF;
        }
        __syncthreads();
        for (int i = t; i < count; i += 256) col[base + i] = srt[i];
    } else {  // fallback (not expected): direct global scatter
        for (int i = t; i < count; i += 256) {
            int v = temp[base + i];
            int p = atomicAdd(&cur[(v >> 16) & (BINW - 1)], 1);
            col[base + p] = v & 0xFFFF;
        }
    }
}

// ---------------- W pack: fp32 [k][n] -> MFMA B-fragment order, split bf16 hi/lo ----------------
// 15 matrices (5 per layer: Wl_isa, Wl_rev, Wsum=Wr_isa+Wr_rev, Wl_rel, Wr_rel).
// B-operand layout: n = ct*16 + (lane&15), k = kc*32 + (lane>>4)*8 + j.

struct WSrc { const float* a[15]; const float* b[15]; };

__global__ __launch_bounds__(256) void pack_w_kernel(WSrc src, short* __restrict__ whi,
                                                     short* __restrict__ wlo) {
    int idx = blockIdx.x * 256 + threadIdx.x;   // (mat, kc, ct, lane)
    if (idx >= 15 * 4 * 8 * 64) return;
    int lane = idx & 63;
    int ct = (idx >> 6) & 7;
    int kc = (idx >> 9) & 3;
    int mat = idx >> 11;
    const float* A = src.a[mat];
    const float* Bp = src.b[mat];
    int n = ct * 16 + (lane & 15);
    int kbase = kc * 32 + (lane >> 4) * 8;
    size_t o = (size_t)idx * 8;
    for (int j = 0; j < 8; ++j) {
        float v = A[(size_t)(kbase + j) * H + n];
        if (Bp) v += Bp[(size_t)(kbase + j) * H + n];
        short h = f2bf(v);
        whi[o + j] = h;
        wlo[o + j] = f2bf(v - bf2f(h));
    }
}

// ---------------- fp32 -> fp16 mirror convert (layer-0 inputs) ----------------

__global__ __launch_bounds__(256) void cvt16_kernel(const float* __restrict__ x,
                                                    _Float16* __restrict__ y, int n4) {
    int i = blockIdx.x * 256 + threadIdx.x;
    if (i >= n4) return;
    f32x4 v = *(const f32x4*)&x[(size_t)i * 4];
    half4v h;
#pragma unroll
    for (int k = 0; k < 4; ++k) h[k] = (_Float16)v[k];
    *(half4v*)&y[(size_t)i * 4] = h;
}

// ---------------- merged per-layer segment mean (scalar-base fp16 gather) ----------------
// Whole wave processes one dst row; lane covers 2 features (voff = lane*2).
// readfirstlane forces the gathered row base into SGPR -> global_load saddr+voffset:
// zero per-edge VALU address math. 16-deep chunks keep 16 gathers in flight.
// Tail: clamp index to the last valid edge (same line -> cache hit) and weight 0.

__device__ __forceinline__ float2 seg16(const _Float16* __restrict__ x,
                                        const int* __restrict__ col,
                                        int beg, int end, int voff) {
    float ax0 = 0.f, ax1 = 0.f, ax2 = 0.f, ax3 = 0.f;
    float ay0 = 0.f, ay1 = 0.f, ay2 = 0.f, ay3 = 0.f;
    int e = beg;
    while (e + 16 <= end) {               // uniform loop control
        half2v v[16];
#pragma unroll
        for (int i = 0; i < 16; ++i) {
            int si = __builtin_amdgcn_readfirstlane(col[e + i]);   // SGPR row index
            v[i] = *(const half2v*)(x + (size_t)si * H + voff);    // saddr + voffset
        }
#pragma unroll
        for (int i = 0; i < 16; i += 4) {
            ax0 += (float)v[i + 0][0]; ay0 += (float)v[i + 0][1];
            ax1 += (float)v[i + 1][0]; ay1 += (float)v[i + 1][1];
            ax2 += (float)v[i + 2][0]; ay2 += (float)v[i + 2][1];
            ax3 += (float)v[i + 3][0]; ay3 += (float)v[i + 3][1];
        }
        e += 16;
    }
    int rem = end - e;
    if (rem > 0) {                        // uniform branch
        int last = end - 1;
        half2v v[16];
#pragma unroll
        for (int i = 0; i < 16; ++i) {
            int p = e + i; if (p > last) p = last;                 // SALU clamp, no OOB
            int si = __builtin_amdgcn_readfirstlane(col[p]);
            v[i] = *(const half2v*)(x + (size_t)si * H + voff);
        }
#pragma unroll
        for (int i = 0; i < 16; ++i) {
            float m = (i < rem) ? 1.0f : 0.0f;
            float fx = (float)v[i][0], fy = (float)v[i][1];
            if ((i & 3) == 0) { ax0 = fmaf(fx, m, ax0); ay0 = fmaf(fy, m, ay0); }
            else if ((i & 3) == 1) { ax1 = fmaf(fx, m, ax1); ay1 = fmaf(fy, m, ay1); }
            else if ((i & 3) == 2) { ax2 = fmaf(fx, m, ax2); ay2 = fmaf(fy, m, ay2); }
            else { ax3 = fmaf(fx, m, ax3); ay3 = fmaf(fy, m, ay3); }
        }
    }
    float sx = (ax0 + ax1) + (ax2 + ax3);
    float sy = (ay0 + ay1) + (ay2 + ay3);
    int c = end - beg; if (c < 1) c = 1;
    float inv = 1.0f / (float)c;
    return (float2){sx * inv, sy * inv};
}

__global__ __launch_bounds__(256) void agg_all_kernel(
    const _Float16* __restrict__ xp, const _Float16* __restrict__ xg,
    const int* __restrict__ rowptr, const int* __restrict__ col,
    float* __restrict__ M1, float* __restrict__ M2, float* __restrict__ M3,
    int NPn, int NGn) {
    int wl = __builtin_amdgcn_readfirstlane((int)threadIdx.x >> 6);  // SGPR wave id
    int w = (blockIdx.x << 2) + wl;
    int lane = threadIdx.x & 63;
    int voff = lane * 2;
    if (w < NPn) {
        float2 r1 = seg16(xp, col, rowptr[w], rowptr[w + 1], voff);
        *(float2*)&M1[(size_t)w * H + voff] = r1;
        int b = NPn + NGn + w;
        float2 r2 = seg16(xg, col, rowptr[b], rowptr[b + 1], voff);
        *(float2*)&M2[(size_t)w * H + voff] = r2;
    } else if (w < NPn + NGn) {
        float2 r3 = seg16(xp, col, rowptr[w], rowptr[w + 1], voff);
        *(float2*)&M3[(size_t)(w - NPn) * H + voff] = r3;
    }
}

// ---------------- split-bf16 MFMA GEMM, double-buffered B prefetch (proven R6) ----------------
// A-inputs: fp32 (split to bf16 hi/lo on stage) OR pre-split hi/lo planes (pure copy).
// Epilogue: fp16 mirror (gathers/decoder) + split-bf16 hi/lo planes (next layer's A)
// -- bit-identical to the old fp32-store-then-resplit path, with half the bytes.
// In-place safety: block b reads plane rows [r0,r0+64) (incl. the n_rows-1 clamp, which
// stays inside the last block's own range) strictly before its epilogue writes them;
// no cross-block overlap.

struct GIn { const float* f; const short* hi; const short* lo; };

template <int NIN>
__global__ __launch_bounds__(256, 3) void gemm_mfma(
    GIn a0, GIn a1, GIn a2,
    const short* __restrict__ whi, const short* __restrict__ wlo,
    int mat0, int mat1, int mat2,
    const float* __restrict__ b0, const float* __restrict__ b1,
    _Float16* __restrict__ out16, short* __restrict__ ohi, short* __restrict__ olo,
    int n_rows, int relu) {
    __shared__ short Ahi[64 * RS];
    __shared__ short Alo[64 * RS];
    const int tid = threadIdx.x;
    const int lane = tid & 63;
    const int wave = tid >> 6;
    const int r0 = blockIdx.x * 64;
    const int ct0 = wave * 2;
    const int m16 = lane & 15;
    const int acol = (lane >> 4) * 8;

    f32x4 acc[4][2];
#pragma unroll
    for (int mt = 0; mt < 4; ++mt)
#pragma unroll
        for (int c = 0; c < 2; ++c) acc[mt][c] = (f32x4){0.f, 0.f, 0.f, 0.f};

    const GIn ins[3] = {a0, a1, a2};
    const int marr[3] = {mat0, mat1, mat2};

    short8 bh[2][2], bl[2][2];
    {
        const short* wh = whi + (size_t)marr[0] * (H * H);
        const short* wl = wlo + (size_t)marr[0] * (H * H);
        size_t f0 = ((size_t)ct0 * 64 + lane) * 8;
        bh[0][0] = *(const short8*)&wh[f0];
        bh[0][1] = *(const short8*)&wh[f0 + 512];
        bl[0][0] = *(const short8*)&wl[f0];
        bl[0][1] = *(const short8*)&wl[f0 + 512];
    }

#pragma unroll
    for (int m = 0; m < NIN; ++m) {
        const short* __restrict__ wh = whi + (size_t)marr[m] * (H * H);
        const short* __restrict__ wl = wlo + (size_t)marr[m] * (H * H);
        __syncthreads();
        if (ins[m].hi) {                    // pre-split planes: pure copy
#pragma unroll
            for (int i = 0; i < 8; ++i) {
                int f = tid + i * 256;
                int row = f >> 5;
                int c4 = (f & 31) * 4;
                int gr = r0 + row;
                if (gr >= n_rows) gr = n_rows - 1;
                size_t o = (size_t)gr * H + c4;
                *(short4v*)&Ahi[row * RS + c4] = *(const short4v*)&ins[m].hi[o];
                *(short4v*)&Alo[row * RS + c4] = *(const short4v*)&ins[m].lo[o];
            }
        } else {                            // fp32: split on stage
            const float* __restrict__ A = ins[m].f;
#pragma unroll
            for (int i = 0; i < 8; ++i) {
                int f = tid + i * 256;
                int row = f >> 5;
                int c4 = (f & 31) * 4;
                int gr = r0 + row;
                if (gr >= n_rows) gr = n_rows - 1;
                float4 v = *(const float4*)&A[(size_t)gr * H + c4];
                short h0 = f2bf(v.x), h1 = f2bf(v.y), h2 = f2bf(v.z), h3 = f2bf(v.w);
                *(short4v*)&Ahi[row * RS + c4] = (short4v){h0, h1, h2, h3};
                *(short4v*)&Alo[row * RS + c4] =
                    (short4v){f2bf(v.x - bf2f(h0)), f2bf(v.y - bf2f(h1)),
                              f2bf(v.z - bf2f(h2)), f2bf(v.w - bf2f(h3))};
            }
        }
        __syncthreads();
#pragma unroll
        for (int kc = 0; kc < 4; ++kc) {
            if (kc < 3) {
                int nb = (kc + 1) & 1;
                size_t f = ((size_t)((kc + 1) * 8 + ct0) * 64 + lane) * 8;
                bh[nb][0] = *(const short8*)&wh[f];
                bh[nb][1] = *(const short8*)&wh[f + 512];
                bl[nb][0] = *(const short8*)&wl[f];
                bl[nb][1] = *(const short8*)&wl[f + 512];
            } else if (m + 1 < NIN) {
                const short* wh2 = whi + (size_t)marr[m + 1] * (H * H);
                const short* wl2 = wlo + (size_t)marr[m + 1] * (H * H);
                size_t f = ((size_t)ct0 * 64 + lane) * 8;
                bh[0][0] = *(const short8*)&wh2[f];
                bh[0][1] = *(const short8*)&wh2[f + 512];
                bl[0][0] = *(const short8*)&wl2[f];
                bl[0][1] = *(const short8*)&wl2[f + 512];
            }
            int cb = kc & 1;
#pragma unroll
            for (int mt = 0; mt < 4; ++mt) {
                short8 ah = *(const short8*)&Ahi[(mt * 16 + m16) * RS + kc * 32 + acol];
                short8 al = *(const short8*)&Alo[(mt * 16 + m16) * RS + kc * 32 + acol];
#pragma unroll
                for (int c = 0; c < 2; ++c) {
                    acc[mt][c] = __builtin_amdgcn_mfma_f32_16x16x32_bf16(ah, bh[cb][c], acc[mt][c], 0, 0, 0);
                    acc[mt][c] = __builtin_amdgcn_mfma_f32_16x16x32_bf16(al, bh[cb][c], acc[mt][c], 0, 0, 0);
                    acc[mt][c] = __builtin_amdgcn_mfma_f32_16x16x32_bf16(ah, bl[cb][c], acc[mt][c], 0, 0, 0);
                }
            }
        }
    }

    const int rquad = (lane >> 4) * 4;
    const int ncol = lane & 15;
#pragma unroll
    for (int c = 0; c < 2; ++c) {
        int n = (ct0 + c) * 16 + ncol;
        float bs = b0[n];
        if (b1) bs += b1[n];
#pragma unroll
        for (int mt = 0; mt < 4; ++mt) {
#pragma unroll
            for (int reg = 0; reg < 4; ++reg) {
                int gr = r0 + mt * 16 + rquad + reg;
                if (gr < n_rows) {
                    float v = acc[mt][c][reg] + bs;
                    if (relu) v = v > 0.f ? v : 0.01f * v;
                    size_t o = (size_t)gr * H + n;
                    out16[o] = (_Float16)v;
                    short h = f2bf(v);
                    ohi[o] = h;
                    olo[o] = f2bf(v - bf2f(h));
                }
            }
        }
    }
}

// ---------------- edge decoder: sigmoid(dot(xp[i], xg[j])) on fp16 mirrors ----------------

__global__ __launch_bounds__(256) void scores_kernel(const _Float16* __restrict__ xp,
                                                     const _Float16* __restrict__ xg,
                                                     const int* __restrict__ eli, int E,
                                                     float* __restrict__ out) {
    int lane16 = threadIdx.x & 15;
    int sub = threadIdx.x >> 4;     // 16 edges per block
    int e = blockIdx.x * 16 + sub;
    if (e >= E) return;
    int ip = eli[e];
    int ig = eli[E + e];
    half8v a = *(const half8v*)&xp[(size_t)ip * H + lane16 * 8];
    half8v b = *(const half8v*)&xg[(size_t)ig * H + lane16 * 8];
    float s = 0.f;
#pragma unroll
    for (int k = 0; k < 8; ++k) s += (float)a[k] * (float)b[k];
#pragma unroll
    for (int off = 8; off; off >>= 1) s += __shfl_xor(s, off, 16);
    if (lane16 == 0) out[e] = 1.0f / (1.0f + expf(-s));
}

// ---------------- host ----------------

extern "C" void kernel_launch(void* const* d_in, const int* in_sizes, int n_in,
                              void* d_out, int out_size, void* d_ws, size_t ws_size,
                              hipStream_t stream) {
    const float* x_pheno = (const float*)d_in[0];
    const float* x_gene  = (const float*)d_in[1];
    const float* Wl_isa  = (const float*)d_in[2];
    const float* bl_isa  = (const float*)d_in[3];
    const float* Wr_isa  = (const float*)d_in[4];
    const float* Wl_rel  = (const float*)d_in[5];
    const float* bl_rel  = (const float*)d_in[6];
    const float* Wr_rel  = (const float*)d_in[7];
    const float* Wl_rev  = (const float*)d_in[8];
    const float* bl_rev  = (const float*)d_in[9];
    const float* Wr_rev  = (const float*)d_in[10];
    const int* e_isa = (const int*)d_in[11];
    const int* e_rel = (const int*)d_in[12];
    const int* e_rev = (const int*)d_in[13];
    const int* e_lbl = (const int*)d_in[14];
    const int E_isa = in_sizes[11] / 2;
    const int E_rel = in_sizes[12] / 2;
    const int E_rev = in_sizes[13] / 2;
    const int E_lbl = in_sizes[14] / 2;
    const int NP = in_sizes[0] / H;
    const int NG = in_sizes[1] / H;
    const int NMAX = NP > NG ? NP : NG;
    const int n_tot = NP + NG + NP;
    const int E_tot = E_isa + E_rel + E_rev;
    const int nb = (n_tot + 1023) / 1024;
    const int nbins = (n_tot + BINW - 1) / BINW;

    char* ws = (char*)d_ws;
    auto alloc = [&](size_t bytes) -> char* {
        char* p = ws;
        ws += (bytes + 255) & ~(size_t)255;
        return p;
    };
    float* M1 = (float*)alloc((size_t)NMAX * H * sizeof(float));
    float* M2 = (float*)alloc((size_t)NMAX * H * sizeof(float));
    float* M3 = (float*)alloc((size_t)NMAX * H * sizeof(float));
    int* cnt     = (int*)alloc((size_t)n_tot * 4);
    int* rowptr  = (int*)alloc((size_t)(n_tot + 1) * 4);
    int* col     = (int*)alloc((size_t)E_tot * 4);
    int* temp    = (int*)alloc((size_t)E_tot * 4);
    int* bin_cur = (int*)alloc((size_t)nbins * 16 * 4);   // 64B-strided counters
    int* partial = (int*)alloc((size_t)1024 * 4);
    short* whi = (short*)alloc((size_t)15 * H * H * sizeof(short));
    short* wlo = (short*)alloc((size_t)15 * H * H * sizeof(short));
    _Float16* xp16 = (_Float16*)alloc((size_t)NP * H * sizeof(_Float16));
    _Float16* xg16 = (_Float16*)alloc((size_t)NG * H * sizeof(_Float16));
    short* xph = (short*)alloc((size_t)NP * H * sizeof(short));
    short* xpl = (short*)alloc((size_t)NP * H * sizeof(short));
    short* xgh = (short*)alloc((size_t)NG * H * sizeof(short));
    short* xgl = (short*)alloc((size_t)NG * H * sizeof(short));

    // ---- CSR build (every call; ws is re-poisoned by the harness) ----
    hipMemsetAsync(cnt, 0, (size_t)n_tot * 4, stream);
    count_all_kernel<<<(E_tot + 255) / 256, 256, 0, stream>>>(
        e_isa, E_isa, e_rel, E_rel, e_rev, E_rev, cnt, NP, NG);
    scan_pass1<<<nb, 256, 0, stream>>>(cnt, n_tot, partial);
    scan_pass2<<<1, 1024, 0, stream>>>(partial, nb, &rowptr[n_tot]);
    scan_pass3<<<nb, 256, 0, stream>>>(cnt, n_tot, partial, rowptr);
    bin_init_kernel<<<(nbins + 255) / 256, 256, 0, stream>>>(rowptr, bin_cur, nbins, n_tot);
    bin_scatter_kernel<<<(E_tot + KEDGE - 1) / KEDGE, 256, 0, stream>>>(
        e_isa, E_isa, e_rel, E_rel, e_rev, E_rev, bin_cur, temp, NP, NG, nbins, E_tot);
    bin_sort_kernel<<<nbins, 256, 0, stream>>>(rowptr, temp, col, n_tot);

    // ---- W pack: per layer slots {Wl_isa, Wl_rev, Wsum=Wr_isa+Wr_rev, Wl_rel, Wr_rel} ----
    WSrc src;
    for (int l = 0; l < 3; ++l) {
        src.a[l * 5 + 0] = Wl_isa + (size_t)l * H * H;  src.b[l * 5 + 0] = nullptr;
        src.a[l * 5 + 1] = Wl_rev + (size_t)l * H * H;  src.b[l * 5 + 1] = nullptr;
        src.a[l * 5 + 2] = Wr_isa + (size_t)l * H * H;  src.b[l * 5 + 2] = Wr_rev + (size_t)l * H * H;
        src.a[l * 5 + 3] = Wl_rel + (size_t)l * H * H;  src.b[l * 5 + 3] = nullptr;
        src.a[l * 5 + 4] = Wr_rel + (size_t)l * H * H;  src.b[l * 5 + 4] = nullptr;
    }
    pack_w_kernel<<<(15 * 4 * 8 * 64 + 255) / 256, 256, 0, stream>>>(src, whi, wlo);

    // ---- layer-0 fp16 mirrors of the inputs ----
    cvt16_kernel<<<(NP * H / 4 + 255) / 256, 256, 0, stream>>>(x_pheno, xp16, NP * H / 4);
    cvt16_kernel<<<(NG * H / 4 + 255) / 256, 256, 0, stream>>>(x_gene, xg16, NG * H / 4);

    // ---- 3 layers ----
    // Activations live in {xp16 (gather mirror), xph/xpl (split-bf16 GEMM planes)};
    // M1/M2/M3 are per-layer fp32 scratch. agg reads mirrors, then GEMMs overwrite them
    // in-place (block-local read-before-write; stream-ordered vs agg).
    const short *pph = nullptr, *ppl = nullptr, *pgh = nullptr, *pgl = nullptr;
    for (int l = 0; l < 3; ++l) {
        agg_all_kernel<<<(NP + NG + 3) / 4, 256, 0, stream>>>(
            xp16, xg16, rowptr, col, M1, M2, M3, NP, NG);
        int relu = (l < 2) ? 1 : 0;
        const float* bli = bl_isa + (size_t)l * H;
        const float* blv = bl_rev + (size_t)l * H;
        const float* blr = bl_rel + (size_t)l * H;
        GIn a0{M1, nullptr, nullptr};
        GIn a1{M2, nullptr, nullptr};
        GIn a2{l == 0 ? x_pheno : nullptr, pph, ppl};
        // new_p = M1@Wl_isa + M2@Wl_rev + xp@(Wr_isa+Wr_rev) + bl_isa + bl_rev
        gemm_mfma<3><<<(NP + 63) / 64, 256, 0, stream>>>(
            a0, a1, a2, whi, wlo, l * 5 + 0, l * 5 + 1, l * 5 + 2, bli, blv,
            xp16, xph, xpl, NP, relu);
        GIn g0{M3, nullptr, nullptr};
        GIn g1{l == 0 ? x_gene : nullptr, pgh, pgl};
        GIn g2{nullptr, nullptr, nullptr};
        // new_g = M3@Wl_rel + xg@Wr_rel + bl_rel
        gemm_mfma<2><<<(NG + 63) / 64, 256, 0, stream>>>(
            g0, g1, g2, whi, wlo, l * 5 + 3, l * 5 + 4, 0, blr, nullptr,
            xg16, xgh, xgl, NG, relu);
        pph = xph; ppl = xpl; pgh = xgh; pgl = xgl;
    }

    // ---- decoder (reads final-layer fp16 mirrors) ----
    scores_kernel<<<(E_lbl + 15) / 16, 256, 0, stream>>>(xp16, xg16, e_lbl, E_lbl, (float*)d_out);
}

// Round 4
// 669.821 us; speedup vs baseline: 1.4644x; 1.1367x over previous
//
#include <hip/hip_runtime.h>
#include <hip/hip_bf16.h>
#include <math.h>

#define H 128
#define RS 136    // LDS row stride in shorts (128 + 8 pad; keeps ds_read_b128 16B-aligned)
#define BSH 9     // bin shift: 512 nodes per bin
#define BINW 512
#define BCAP 11264  // max edges/bin for LDS sort (expected max ~10.6k at deg-20, 512 nodes)
#define KEDGE 4096  // edges per partition block
#define EPT 16      // edges per thread (KEDGE/256)
#define MAXBINS 1024

typedef __attribute__((ext_vector_type(8))) short short8;
typedef __attribute__((ext_vector_type(4))) short short4v;
typedef __attribute__((ext_vector_type(4))) float f32x4;
typedef __attribute__((ext_vector_type(2))) _Float16 half2v;
typedef __attribute__((ext_vector_type(4))) _Float16 half4v;
typedef __attribute__((ext_vector_type(8))) _Float16 half8v;

// fp32 -> bf16 (RNE); values here are finite (no NaN handling needed)
__device__ __forceinline__ short f2bf(float f) {
    unsigned u = __float_as_uint(f);
    u += 0x7fff + ((u >> 16) & 1);
    return (short)(u >> 16);
}
__device__ __forceinline__ float bf2f(short h) {
    return __uint_as_float(((unsigned)(unsigned short)h) << 16);
}

// ---------------- CSR build (count-free: bin totals -> scatter -> in-bin sort+rowptr) --------
// Node space concatenated: [NP(isa) | NG(rel) | NP(rev)].

// stage 1: per-bin edge totals. LDS histogram per block, ONE padded global atomic per
// touched bin (~294 bins x ~611 blocks ~= 180k atomics on 64B-strided counters),
// replacing 2.5M node-granular atomics (the old count_all: 105us, 77MB atomic write-bounce).
__global__ __launch_bounds__(256) void bin_count_kernel(
    const int* __restrict__ e0, int E0, const int* __restrict__ e1, int E1,
    const int* __restrict__ e2, int E2, int* __restrict__ bin_tot,
    int NPn, int NGn, int nbins, int E_tot) {
    __shared__ int hist[MAXBINS];
    int t = threadIdx.x;
    for (int i = t; i < nbins; i += 256) hist[i] = 0;
    __syncthreads();
    int base_e = blockIdx.x * KEDGE;
#pragma unroll
    for (int j = 0; j < EPT; ++j) {
        int g = base_e + j * 256 + t;      // coalesced within each j-step
        if (g < E_tot) {
            const int* ed; int E, lo, nbase;
            if (g < E0) { ed = e0; E = E0; lo = g; nbase = 0; }
            else if (g < E0 + E1) { ed = e1; E = E1; lo = g - E0; nbase = NPn; }
            else { ed = e2; E = E2; lo = g - E0 - E1; nbase = NPn + NGn; }
            int gdst = nbase + ed[E + lo];
            atomicAdd(&hist[gdst >> BSH], 1);   // LDS atomic
        }
    }
    __syncthreads();
    for (int i = t; i < nbins; i += 256) {
        int h = hist[i];
        if (h) atomicAdd(&bin_tot[i * 16], h);  // 64B-strided global counter
    }
}

// stage 2: exclusive scan of bin totals -> bin_base[0..nbins]; also init bin_cur frontiers.
__global__ __launch_bounds__(1024) void scan_bins(const int* __restrict__ bin_tot, int nbins,
                                                  int* __restrict__ bin_base,
                                                  int* __restrict__ bin_cur) {
    __shared__ int sh[1024];
    int t = threadIdx.x;
    int v = (t < nbins) ? bin_tot[t * 16] : 0;
    sh[t] = v;
    __syncthreads();
    for (int off = 1; off < 1024; off <<= 1) {
        int u = (t >= off) ? sh[t - off] : 0;
        __syncthreads();
        sh[t] += u;
        __syncthreads();
    }
    if (t < nbins) {
        int ex = sh[t] - v;          // exclusive
        bin_base[t] = ex;
        bin_cur[t * 16] = ex;
    }
    if (t == nbins - 1) bin_base[nbins] = sh[t];
}

// stage 3: block-aggregated partition. Per block: LDS histogram over bins, ONE global
// atomicAdd per touched bin (reserve a contiguous run), then scatter from registers via
// LDS run-cursors.
// payload: src | (local_dst << 16)  (src < 2^16, local_dst < 512 -> bits 16..24)
__global__ __launch_bounds__(256) void bin_scatter_kernel(
    const int* __restrict__ e0, int E0, const int* __restrict__ e1, int E1,
    const int* __restrict__ e2, int E2, int* __restrict__ bin_cur,
    int* __restrict__ temp, int NPn, int NGn, int nbins, int E_tot) {
    __shared__ int hist[MAXBINS];
    __shared__ int cur[MAXBINS];
    int t = threadIdx.x;
    for (int i = t; i < nbins; i += 256) hist[i] = 0;
    __syncthreads();
    int vals[EPT], bins[EPT];
    int base_e = blockIdx.x * KEDGE;
#pragma unroll
    for (int j = 0; j < EPT; ++j) {
        int g = base_e + j * 256 + t;      // coalesced within each j-step
        int b = -1, v = 0;
        if (g < E_tot) {
            const int* ed; int E, lo, nbase;
            if (g < E0) { ed = e0; E = E0; lo = g; nbase = 0; }
            else if (g < E0 + E1) { ed = e1; E = E1; lo = g - E0; nbase = NPn; }
            else { ed = e2; E = E2; lo = g - E0 - E1; nbase = NPn + NGn; }
            int src = ed[lo];
            int gdst = nbase + ed[E + lo];
            v = src | ((gdst & (BINW - 1)) << 16);
            b = gdst >> BSH;
            atomicAdd(&hist[b], 1);        // LDS atomic
        }
        vals[j] = v;
        bins[j] = b;
    }
    __syncthreads();
    for (int i = t; i < nbins; i += 256) {
        int h = hist[i];
        cur[i] = h ? atomicAdd(&bin_cur[i * 16], h) : 0;   // reserve run; cur = global base
    }
    __syncthreads();
#pragma unroll
    for (int j = 0; j < EPT; ++j) {
        if (bins[j] >= 0) {
            int p = atomicAdd(&cur[bins[j]], 1);           // LDS atomic -> global slot
            temp[p] = vals[j];
        }
    }
}

// stage 4: per-bin LDS counting sort. Builds the per-node histogram + scan in LDS
// (producing rowptr for this bin), then places edges; col written fully coalesced.
__global__ __launch_bounds__(256) void bin_sort_kernel(
    const int* __restrict__ bin_base, const int* __restrict__ temp,
    int* __restrict__ col, int* __restrict__ rowptr, int n_tot, int nbins) {
    __shared__ int srt[BCAP];
    __shared__ int cur[BINW];
    __shared__ int pfx[BINW];
    __shared__ int red[256];
    int b = blockIdx.x;
    int start = b << BSH;
    int nodes = n_tot - start; if (nodes > BINW) nodes = BINW;
    int t = threadIdx.x;
    int base = bin_base[b];
    int count = bin_base[b + 1] - base;
    // per-node histogram of this bin's payloads
    for (int i = t; i < BINW; i += 256) cur[i] = 0;
    __syncthreads();
    for (int i = t; i < count; i += 256)
        atomicAdd(&cur[(temp[base + i] >> 16) & (BINW - 1)], 1);
    __syncthreads();
    // exclusive scan of 512 counts (2 per thread + 256-wide Hillis-Steele)
    int a0 = cur[2 * t], a1 = cur[2 * t + 1];
    red[t] = a0 + a1;
    __syncthreads();
    for (int off = 1; off < 256; off <<= 1) {
        int u = (t >= off) ? red[t - off] : 0;
        __syncthreads();
        red[t] += u;
        __syncthreads();
    }
    int excl = red[t] - (a0 + a1);
    pfx[2 * t] = excl;
    pfx[2 * t + 1] = excl + a0;
    __syncthreads();
    // rowptr for this bin (boundary start+BINW written by the next bin; last bin: n_tot)
    for (int i = t; i < nodes; i += 256) rowptr[start + i] = base + pfx[i];
    if (b == nbins - 1 && t == 0) rowptr[n_tot] = base + count;
    // reset cursors to local starts
    for (int i = t; i < BINW; i += 256) cur[i] = pfx[i];
    __syncthreads();
    if (count <= BCAP) {
        for (int i = t; i < count; i += 256) {
            int v = temp[base + i];
            int p = atomicAdd(&cur[(v >> 16) & (BINW - 1)], 1);
            srt[p] = v & 0xFFFF;
        }
        __syncthreads();
        for (int i = t; i < count; i += 256) col[base + i] = srt[i];
    } else {  // fallback (not expected): direct global scatter
        for (int i = t; i < count; i += 256) {
            int v = temp[base + i];
            int p = atomicAdd(&cur[(v >> 16) & (BINW - 1)], 1);
            col[base + p] = v & 0xFFFF;
        }
    }
}

// ---------------- W pack: fp32 [k][n] -> MFMA B-fragment order, split bf16 hi/lo ----------------
// 15 matrices (5 per layer: Wl_isa, Wl_rev, Wsum=Wr_isa+Wr_rev, Wl_rel, Wr_rel).
// B-operand layout: n = ct*16 + (lane&15), k = kc*32 + (lane>>4)*8 + j.

struct WSrc { const float* a[15]; const float* b[15]; };

__global__ __launch_bounds__(256) void pack_w_kernel(WSrc src, short* __restrict__ whi,
                                                     short* __restrict__ wlo) {
    int idx = blockIdx.x * 256 + threadIdx.x;   // (mat, kc, ct, lane)
    if (idx >= 15 * 4 * 8 * 64) return;
    int lane = idx & 63;
    int ct = (idx >> 6) & 7;
    int kc = (idx >> 9) & 3;
    int mat = idx >> 11;
    const float* A = src.a[mat];
    const float* Bp = src.b[mat];
    int n = ct * 16 + (lane & 15);
    int kbase = kc * 32 + (lane >> 4) * 8;
    size_t o = (size_t)idx * 8;
    for (int j = 0; j < 8; ++j) {
        float v = A[(size_t)(kbase + j) * H + n];
        if (Bp) v += Bp[(size_t)(kbase + j) * H + n];
        short h = f2bf(v);
        whi[o + j] = h;
        wlo[o + j] = f2bf(v - bf2f(h));
    }
}

// ---------------- fp32 -> fp16 mirror convert (layer-0 inputs) ----------------

__global__ __launch_bounds__(256) void cvt16_kernel(const float* __restrict__ x,
                                                    _Float16* __restrict__ y, int n4) {
    int i = blockIdx.x * 256 + threadIdx.x;
    if (i >= n4) return;
    f32x4 v = *(const f32x4*)&x[(size_t)i * 4];
    half4v h;
#pragma unroll
    for (int k = 0; k < 4; ++k) h[k] = (_Float16)v[k];
    *(half4v*)&y[(size_t)i * 4] = h;
}

// ---------------- merged per-layer segment mean (scalar-base fp16 gather) ----------------
// Whole wave processes one dst row; lane covers 2 features (voff = lane*2).
// readfirstlane forces the gathered row base into SGPR -> global_load saddr+voffset:
// zero per-edge VALU address math. 16-deep chunks keep 16 gathers in flight.
// Tail: clamp index to the last valid edge (same line -> cache hit) and weight 0.

__device__ __forceinline__ float2 seg16(const _Float16* __restrict__ x,
                                        const int* __restrict__ col,
                                        int beg, int end, int voff) {
    float ax0 = 0.f, ax1 = 0.f, ax2 = 0.f, ax3 = 0.f;
    float ay0 = 0.f, ay1 = 0.f, ay2 = 0.f, ay3 = 0.f;
    int e = beg;
    while (e + 16 <= end) {               // uniform loop control
        half2v v[16];
#pragma unroll
        for (int i = 0; i < 16; ++i) {
            int si = __builtin_amdgcn_readfirstlane(col[e + i]);   // SGPR row index
            v[i] = *(const half2v*)(x + (size_t)si * H + voff);    // saddr + voffset
        }
#pragma unroll
        for (int i = 0; i < 16; i += 4) {
            ax0 += (float)v[i + 0][0]; ay0 += (float)v[i + 0][1];
            ax1 += (float)v[i + 1][0]; ay1 += (float)v[i + 1][1];
            ax2 += (float)v[i + 2][0]; ay2 += (float)v[i + 2][1];
            ax3 += (float)v[i + 3][0]; ay3 += (float)v[i + 3][1];
        }
        e += 16;
    }
    int rem = end - e;
    if (rem > 0) {                        // uniform branch
        int last = end - 1;
        half2v v[16];
#pragma unroll
        for (int i = 0; i < 16; ++i) {
            int p = e + i; if (p > last) p = last;                 // SALU clamp, no OOB
            int si = __builtin_amdgcn_readfirstlane(col[p]);
            v[i] = *(const half2v*)(x + (size_t)si * H + voff);
        }
#pragma unroll
        for (int i = 0; i < 16; ++i) {
            float m = (i < rem) ? 1.0f : 0.0f;
            float fx = (float)v[i][0], fy = (float)v[i][1];
            if ((i & 3) == 0) { ax0 = fmaf(fx, m, ax0); ay0 = fmaf(fy, m, ay0); }
            else if ((i & 3) == 1) { ax1 = fmaf(fx, m, ax1); ay1 = fmaf(fy, m, ay1); }
            else if ((i & 3) == 2) { ax2 = fmaf(fx, m, ax2); ay2 = fmaf(fy, m, ay2); }
            else { ax3 = fmaf(fx, m, ax3); ay3 = fmaf(fy, m, ay3); }
        }
    }
    float sx = (ax0 + ax1) + (ax2 + ax3);
    float sy = (ay0 + ay1) + (ay2 + ay3);
    int c = end - beg; if (c < 1) c = 1;
    float inv = 1.0f / (float)c;
    return (float2){sx * inv, sy * inv};
}

__global__ __launch_bounds__(256) void agg_all_kernel(
    const _Float16* __restrict__ xp, const _Float16* __restrict__ xg,
    const int* __restrict__ rowptr, const int* __restrict__ col,
    float* __restrict__ M1, float* __restrict__ M2, float* __restrict__ M3,
    int NPn, int NGn) {
    int wl = __builtin_amdgcn_readfirstlane((int)threadIdx.x >> 6);  // SGPR wave id
    int w = (blockIdx.x << 2) + wl;
    int lane = threadIdx.x & 63;
    int voff = lane * 2;
    if (w < NPn) {
        float2 r1 = seg16(xp, col, rowptr[w], rowptr[w + 1], voff);
        *(float2*)&M1[(size_t)w * H + voff] = r1;
        int b = NPn + NGn + w;
        float2 r2 = seg16(xg, col, rowptr[b], rowptr[b + 1], voff);
        *(float2*)&M2[(size_t)w * H + voff] = r2;
    } else if (w < NPn + NGn) {
        float2 r3 = seg16(xp, col, rowptr[w], rowptr[w + 1], voff);
        *(float2*)&M3[(size_t)(w - NPn) * H + voff] = r3;
    }
}

// ---------------- split-bf16 MFMA GEMM, double-buffered B prefetch (proven R6) ----------------
// A-inputs: fp32 (split to bf16 hi/lo on stage) OR pre-split hi/lo planes (pure copy).
// Epilogue: fp16 mirror (gathers/decoder) + split-bf16 hi/lo planes (next layer's A)
// -- bit-identical to the old fp32-store-then-resplit path, with half the bytes.
// In-place safety: block b reads plane rows [r0,r0+64) (incl. the n_rows-1 clamp, which
// stays inside the last block's own range) strictly before its epilogue writes them;
// no cross-block overlap.

struct GIn { const float* f; const short* hi; const short* lo; };

template <int NIN>
__global__ __launch_bounds__(256, 3) void gemm_mfma(
    GIn a0, GIn a1, GIn a2,
    const short* __restrict__ whi, const short* __restrict__ wlo,
    int mat0, int mat1, int mat2,
    const float* __restrict__ b0, const float* __restrict__ b1,
    _Float16* __restrict__ out16, short* __restrict__ ohi, short* __restrict__ olo,
    int n_rows, int relu) {
    __shared__ short Ahi[64 * RS];
    __shared__ short Alo[64 * RS];
    const int tid = threadIdx.x;
    const int lane = tid & 63;
    const int wave = tid >> 6;
    const int r0 = blockIdx.x * 64;
    const int ct0 = wave * 2;
    const int m16 = lane & 15;
    const int acol = (lane >> 4) * 8;

    f32x4 acc[4][2];
#pragma unroll
    for (int mt = 0; mt < 4; ++mt)
#pragma unroll
        for (int c = 0; c < 2; ++c) acc[mt][c] = (f32x4){0.f, 0.f, 0.f, 0.f};

    const GIn ins[3] = {a0, a1, a2};
    const int marr[3] = {mat0, mat1, mat2};

    short8 bh[2][2], bl[2][2];
    {
        const short* wh = whi + (size_t)marr[0] * (H * H);
        const short* wl = wlo + (size_t)marr[0] * (H * H);
        size_t f0 = ((size_t)ct0 * 64 + lane) * 8;
        bh[0][0] = *(const short8*)&wh[f0];
        bh[0][1] = *(const short8*)&wh[f0 + 512];
        bl[0][0] = *(const short8*)&wl[f0];
        bl[0][1] = *(const short8*)&wl[f0 + 512];
    }

#pragma unroll
    for (int m = 0; m < NIN; ++m) {
        const short* __restrict__ wh = whi + (size_t)marr[m] * (H * H);
        const short* __restrict__ wl = wlo + (size_t)marr[m] * (H * H);
        __syncthreads();
        if (ins[m].hi) {                    // pre-split planes: pure copy
#pragma unroll
            for (int i = 0; i < 8; ++i) {
                int f = tid + i * 256;
                int row = f >> 5;
                int c4 = (f & 31) * 4;
                int gr = r0 + row;
                if (gr >= n_rows) gr = n_rows - 1;
                size_t o = (size_t)gr * H + c4;
                *(short4v*)&Ahi[row * RS + c4] = *(const short4v*)&ins[m].hi[o];
                *(short4v*)&Alo[row * RS + c4] = *(const short4v*)&ins[m].lo[o];
            }
        } else {                            // fp32: split on stage
            const float* __restrict__ A = ins[m].f;
#pragma unroll
            for (int i = 0; i < 8; ++i) {
                int f = tid + i * 256;
                int row = f >> 5;
                int c4 = (f & 31) * 4;
                int gr = r0 + row;
                if (gr >= n_rows) gr = n_rows - 1;
                float4 v = *(const float4*)&A[(size_t)gr * H + c4];
                short h0 = f2bf(v.x), h1 = f2bf(v.y), h2 = f2bf(v.z), h3 = f2bf(v.w);
                *(short4v*)&Ahi[row * RS + c4] = (short4v){h0, h1, h2, h3};
                *(short4v*)&Alo[row * RS + c4] =
                    (short4v){f2bf(v.x - bf2f(h0)), f2bf(v.y - bf2f(h1)),
                              f2bf(v.z - bf2f(h2)), f2bf(v.w - bf2f(h3))};
            }
        }
        __syncthreads();
#pragma unroll
        for (int kc = 0; kc < 4; ++kc) {
            if (kc < 3) {
                int nb = (kc + 1) & 1;
                size_t f = ((size_t)((kc + 1) * 8 + ct0) * 64 + lane) * 8;
                bh[nb][0] = *(const short8*)&wh[f];
                bh[nb][1] = *(const short8*)&wh[f + 512];
                bl[nb][0] = *(const short8*)&wl[f];
                bl[nb][1] = *(const short8*)&wl[f + 512];
            } else if (m + 1 < NIN) {
                const short* wh2 = whi + (size_t)marr[m + 1] * (H * H);
                const short* wl2 = wlo + (size_t)marr[m + 1] * (H * H);
                size_t f = ((size_t)ct0 * 64 + lane) * 8;
                bh[0][0] = *(const short8*)&wh2[f];
                bh[0][1] = *(const short8*)&wh2[f + 512];
                bl[0][0] = *(const short8*)&wl2[f];
                bl[0][1] = *(const short8*)&wl2[f + 512];
            }
            int cb = kc & 1;
#pragma unroll
            for (int mt = 0; mt < 4; ++mt) {
                short8 ah = *(const short8*)&Ahi[(mt * 16 + m16) * RS + kc * 32 + acol];
                short8 al = *(const short8*)&Alo[(mt * 16 + m16) * RS + kc * 32 + acol];
#pragma unroll
                for (int c = 0; c < 2; ++c) {
                    acc[mt][c] = __builtin_amdgcn_mfma_f32_16x16x32_bf16(ah, bh[cb][c], acc[mt][c], 0, 0, 0);
                    acc[mt][c] = __builtin_amdgcn_mfma_f32_16x16x32_bf16(al, bh[cb][c], acc[mt][c], 0, 0, 0);
                    acc[mt][c] = __builtin_amdgcn_mfma_f32_16x16x32_bf16(ah, bl[cb][c], acc[mt][c], 0, 0, 0);
                }
            }
        }
    }

    const int rquad = (lane >> 4) * 4;
    const int ncol = lane & 15;
#pragma unroll
    for (int c = 0; c < 2; ++c) {
        int n = (ct0 + c) * 16 + ncol;
        float bs = b0[n];
        if (b1) bs += b1[n];
#pragma unroll
        for (int mt = 0; mt < 4; ++mt) {
#pragma unroll
            for (int reg = 0; reg < 4; ++reg) {
                int gr = r0 + mt * 16 + rquad + reg;
                if (gr < n_rows) {
                    float v = acc[mt][c][reg] + bs;
                    if (relu) v = v > 0.f ? v : 0.01f * v;
                    size_t o = (size_t)gr * H + n;
                    out16[o] = (_Float16)v;
                    short h = f2bf(v);
                    ohi[o] = h;
                    olo[o] = f2bf(v - bf2f(h));
                }
            }
        }
    }
}

// ---------------- edge decoder: sigmoid(dot(xp[i], xg[j])) on fp16 mirrors ----------------

__global__ __launch_bounds__(256) void scores_kernel(const _Float16* __restrict__ xp,
                                                     const _Float16* __restrict__ xg,
                                                     const int* __restrict__ eli, int E,
                                                     float* __restrict__ out) {
    int lane16 = threadIdx.x & 15;
    int sub = threadIdx.x >> 4;     // 16 edges per block
    int e = blockIdx.x * 16 + sub;
    if (e >= E) return;
    int ip = eli[e];
    int ig = eli[E + e];
    half8v a = *(const half8v*)&xp[(size_t)ip * H + lane16 * 8];
    half8v b = *(const half8v*)&xg[(size_t)ig * H + lane16 * 8];
    float s = 0.f;
#pragma unroll
    for (int k = 0; k < 8; ++k) s += (float)a[k] * (float)b[k];
#pragma unroll
    for (int off = 8; off; off >>= 1) s += __shfl_xor(s, off, 16);
    if (lane16 == 0) out[e] = 1.0f / (1.0f + expf(-s));
}

// ---------------- host ----------------

extern "C" void kernel_launch(void* const* d_in, const int* in_sizes, int n_in,
                              void* d_out, int out_size, void* d_ws, size_t ws_size,
                              hipStream_t stream) {
    const float* x_pheno = (const float*)d_in[0];
    const float* x_gene  = (const float*)d_in[1];
    const float* Wl_isa  = (const float*)d_in[2];
    const float* bl_isa  = (const float*)d_in[3];
    const float* Wr_isa  = (const float*)d_in[4];
    const float* Wl_rel  = (const float*)d_in[5];
    const float* bl_rel  = (const float*)d_in[6];
    const float* Wr_rel  = (const float*)d_in[7];
    const float* Wl_rev  = (const float*)d_in[8];
    const float* bl_rev  = (const float*)d_in[9];
    const float* Wr_rev  = (const float*)d_in[10];
    const int* e_isa = (const int*)d_in[11];
    const int* e_rel = (const int*)d_in[12];
    const int* e_rev = (const int*)d_in[13];
    const int* e_lbl = (const int*)d_in[14];
    const int E_isa = in_sizes[11] / 2;
    const int E_rel = in_sizes[12] / 2;
    const int E_rev = in_sizes[13] / 2;
    const int E_lbl = in_sizes[14] / 2;
    const int NP = in_sizes[0] / H;
    const int NG = in_sizes[1] / H;
    const int NMAX = NP > NG ? NP : NG;
    const int n_tot = NP + NG + NP;
    const int E_tot = E_isa + E_rel + E_rev;
    const int nbins = (n_tot + BINW - 1) / BINW;

    char* ws = (char*)d_ws;
    auto alloc = [&](size_t bytes) -> char* {
        char* p = ws;
        ws += (bytes + 255) & ~(size_t)255;
        return p;
    };
    float* M1 = (float*)alloc((size_t)NMAX * H * sizeof(float));
    float* M2 = (float*)alloc((size_t)NMAX * H * sizeof(float));
    float* M3 = (float*)alloc((size_t)NMAX * H * sizeof(float));
    int* rowptr  = (int*)alloc((size_t)(n_tot + 1) * 4);
    int* col     = (int*)alloc((size_t)E_tot * 4);
    int* temp    = (int*)alloc((size_t)E_tot * 4);
    int* bin_tot = (int*)alloc((size_t)nbins * 16 * 4);   // 64B-strided counters
    int* bin_cur = (int*)alloc((size_t)nbins * 16 * 4);   // 64B-strided counters
    int* bin_base= (int*)alloc((size_t)(nbins + 1) * 4);
    short* whi = (short*)alloc((size_t)15 * H * H * sizeof(short));
    short* wlo = (short*)alloc((size_t)15 * H * H * sizeof(short));
    _Float16* xp16 = (_Float16*)alloc((size_t)NP * H * sizeof(_Float16));
    _Float16* xg16 = (_Float16*)alloc((size_t)NG * H * sizeof(_Float16));
    short* xph = (short*)alloc((size_t)NP * H * sizeof(short));
    short* xpl = (short*)alloc((size_t)NP * H * sizeof(short));
    short* xgh = (short*)alloc((size_t)NG * H * sizeof(short));
    short* xgl = (short*)alloc((size_t)NG * H * sizeof(short));

    // ---- CSR build (every call; ws is re-poisoned by the harness) ----
    hipMemsetAsync(bin_tot, 0, (size_t)nbins * 16 * 4, stream);
    bin_count_kernel<<<(E_tot + KEDGE - 1) / KEDGE, 256, 0, stream>>>(
        e_isa, E_isa, e_rel, E_rel, e_rev, E_rev, bin_tot, NP, NG, nbins, E_tot);
    scan_bins<<<1, 1024, 0, stream>>>(bin_tot, nbins, bin_base, bin_cur);
    bin_scatter_kernel<<<(E_tot + KEDGE - 1) / KEDGE, 256, 0, stream>>>(
        e_isa, E_isa, e_rel, E_rel, e_rev, E_rev, bin_cur, temp, NP, NG, nbins, E_tot);
    bin_sort_kernel<<<nbins, 256, 0, stream>>>(bin_base, temp, col, rowptr, n_tot, nbins);

    // ---- W pack: per layer slots {Wl_isa, Wl_rev, Wsum=Wr_isa+Wr_rev, Wl_rel, Wr_rel} ----
    WSrc src;
    for (int l = 0; l < 3; ++l) {
        src.a[l * 5 + 0] = Wl_isa + (size_t)l * H * H;  src.b[l * 5 + 0] = nullptr;
        src.a[l * 5 + 1] = Wl_rev + (size_t)l * H * H;  src.b[l * 5 + 1] = nullptr;
        src.a[l * 5 + 2] = Wr_isa + (size_t)l * H * H;  src.b[l * 5 + 2] = Wr_rev + (size_t)l * H * H;
        src.a[l * 5 + 3] = Wl_rel + (size_t)l * H * H;  src.b[l * 5 + 3] = nullptr;
        src.a[l * 5 + 4] = Wr_rel + (size_t)l * H * H;  src.b[l * 5 + 4] = nullptr;
    }
    pack_w_kernel<<<(15 * 4 * 8 * 64 + 255) / 256, 256, 0, stream>>>(src, whi, wlo);

    // ---- layer-0 fp16 mirrors of the inputs ----
    cvt16_kernel<<<(NP * H / 4 + 255) / 256, 256, 0, stream>>>(x_pheno, xp16, NP * H / 4);
    cvt16_kernel<<<(NG * H / 4 + 255) / 256, 256, 0, stream>>>(x_gene, xg16, NG * H / 4);

    // ---- 3 layers ----
    // Activations live in {xp16 (gather mirror), xph/xpl (split-bf16 GEMM planes)};
    // M1/M2/M3 are per-layer fp32 scratch. agg reads mirrors, then GEMMs overwrite them
    // in-place (block-local read-before-write; stream-ordered vs agg).
    const short *pph = nullptr, *ppl = nullptr, *pgh = nullptr, *pgl = nullptr;
    for (int l = 0; l < 3; ++l) {
        agg_all_kernel<<<(NP + NG + 3) / 4, 256, 0, stream>>>(
            xp16, xg16, rowptr, col, M1, M2, M3, NP, NG);
        int relu = (l < 2) ? 1 : 0;
        const float* bli = bl_isa + (size_t)l * H;
        const float* blv = bl_rev + (size_t)l * H;
        const float* blr = bl_rel + (size_t)l * H;
        GIn a0{M1, nullptr, nullptr};
        GIn a1{M2, nullptr, nullptr};
        GIn a2{l == 0 ? x_pheno : nullptr, pph, ppl};
        // new_p = M1@Wl_isa + M2@Wl_rev + xp@(Wr_isa+Wr_rev) + bl_isa + bl_rev
        gemm_mfma<3><<<(NP + 63) / 64, 256, 0, stream>>>(
            a0, a1, a2, whi, wlo, l * 5 + 0, l * 5 + 1, l * 5 + 2, bli, blv,
            xp16, xph, xpl, NP, relu);
        GIn g0{M3, nullptr, nullptr};
        GIn g1{l == 0 ? x_gene : nullptr, pgh, pgl};
        GIn g2{nullptr, nullptr, nullptr};
        // new_g = M3@Wl_rel + xg@Wr_rel + bl_rel
        gemm_mfma<2><<<(NG + 63) / 64, 256, 0, stream>>>(
            g0, g1, g2, whi, wlo, l * 5 + 3, l * 5 + 4, 0, blr, nullptr,
            xg16, xgh, xgl, NG, relu);
        pph = xph; ppl = xpl; pgh = xgh; pgl = xgl;
    }

    // ---- decoder (reads final-layer fp16 mirrors) ----
    scores_kernel<<<(E_lbl + 15) / 16, 256, 0, stream>>>(xp16, xg16, e_lbl, E_lbl, (float*)d_out);
}

// Round 5
// 613.262 us; speedup vs baseline: 1.5994x; 1.0922x over previous
//
#include <hip/hip_runtime.h>
#include <hip/hip_bf16.h>
#include <math.h>

#define H 128
#define RS 136    // LDS row stride in shorts (128 + 8 pad; keeps ds_read_b128 16B-aligned)
#define BSH 9     // bin shift: 512 nodes per bin
#define BINW 512
#define BCAP 11264  // max edges/bin for LDS sort
#define BSLOT 12288 // per-bin slot capacity in temp (direct scatter)
#define KEDGE 4096  // edges per partition block
#define EPT 16      // edges per thread (KEDGE/256)
#define MAXBINS 1024

typedef __attribute__((ext_vector_type(8))) short short8;
typedef __attribute__((ext_vector_type(4))) short short4v;
typedef __attribute__((ext_vector_type(2))) short short2v;
typedef __attribute__((ext_vector_type(4))) float f32x4;
typedef __attribute__((ext_vector_type(2))) _Float16 half2v;
typedef __attribute__((ext_vector_type(4))) _Float16 half4v;
typedef __attribute__((ext_vector_type(8))) _Float16 half8v;

// fp32 -> bf16 (RNE); values here are finite (no NaN handling needed)
__device__ __forceinline__ short f2bf(float f) {
    unsigned u = __float_as_uint(f);
    u += 0x7fff + ((u >> 16) & 1);
    return (short)(u >> 16);
}
__device__ __forceinline__ float bf2f(short h) {
    return __uint_as_float(((unsigned)(unsigned short)h) << 16);
}

// ---------------- CSR build (direct slot scatter -> scan -> in-bin sort+rowptr) ----------
// Node space concatenated: [NP(isa) | NG(rel) | NP(rev)].

// stage 1: block-aggregated partition straight into per-bin slot regions.
// Per block: LDS histogram over bins, ONE global atomicAdd per touched bin (reserve a
// contiguous run in that bin's slot region), then scatter from registers via LDS cursors.
// bin_cur doubles as the per-bin count (starts at 0).
// payload: src | (local_dst << 16)
__global__ __launch_bounds__(256) void bin_scatter_kernel(
    const int* __restrict__ e0, int E0, const int* __restrict__ e1, int E1,
    const int* __restrict__ e2, int E2, int* __restrict__ bin_cur,
    int* __restrict__ temp, int NPn, int NGn, int nbins, int E_tot) {
    __shared__ int hist[MAXBINS];
    __shared__ int cur[MAXBINS];
    int t = threadIdx.x;
    for (int i = t; i < nbins; i += 256) hist[i] = 0;
    __syncthreads();
    int vals[EPT], bins[EPT];
    int base_e = blockIdx.x * KEDGE;
#pragma unroll
    for (int j = 0; j < EPT; ++j) {
        int g = base_e + j * 256 + t;      // coalesced within each j-step
        int b = -1, v = 0;
        if (g < E_tot) {
            const int* ed; int E, lo, nbase;
            if (g < E0) { ed = e0; E = E0; lo = g; nbase = 0; }
            else if (g < E0 + E1) { ed = e1; E = E1; lo = g - E0; nbase = NPn; }
            else { ed = e2; E = E2; lo = g - E0 - E1; nbase = NPn + NGn; }
            int src = ed[lo];
            int gdst = nbase + ed[E + lo];
            v = src | ((gdst & (BINW - 1)) << 16);
            b = gdst >> BSH;
            atomicAdd(&hist[b], 1);        // LDS atomic
        }
        vals[j] = v;
        bins[j] = b;
    }
    __syncthreads();
    for (int i = t; i < nbins; i += 256) {
        int h = hist[i];
        cur[i] = h ? atomicAdd(&bin_cur[i * 16], h) : 0;   // reserve run (local slot base)
    }
    __syncthreads();
#pragma unroll
    for (int j = 0; j < EPT; ++j) {
        if (bins[j] >= 0) {
            int p = atomicAdd(&cur[bins[j]], 1);           // LDS atomic -> local slot
            if (p < BSLOT) temp[(size_t)bins[j] * BSLOT + p] = vals[j];
        }
    }
}

// stage 2: exclusive scan of bin counts -> bin_base[0..nbins].
__global__ __launch_bounds__(1024) void scan_bins(const int* __restrict__ bin_cur, int nbins,
                                                  int* __restrict__ bin_base) {
    __shared__ int sh[1024];
    int t = threadIdx.x;
    int v = 0;
    if (t < nbins) { v = bin_cur[t * 16]; if (v > BSLOT) v = BSLOT; }
    sh[t] = v;
    __syncthreads();
    for (int off = 1; off < 1024; off <<= 1) {
        int u = (t >= off) ? sh[t - off] : 0;
        __syncthreads();
        sh[t] += u;
        __syncthreads();
    }
    if (t < nbins) bin_base[t] = sh[t] - v;    // exclusive
    if (t == nbins - 1) bin_base[nbins] = sh[t];
}

// stage 3: per-bin LDS counting sort. Builds per-node histogram + scan in LDS
// (producing rowptr for this bin), then places edges; col written fully coalesced.
__global__ __launch_bounds__(256) void bin_sort_kernel(
    const int* __restrict__ bin_base, const int* __restrict__ temp,
    int* __restrict__ col, int* __restrict__ rowptr, int n_tot, int nbins) {
    __shared__ int srt[BCAP];
    __shared__ int cur[BINW];
    __shared__ int pfx[BINW];
    __shared__ int red[256];
    int b = blockIdx.x;
    int start = b << BSH;
    int nodes = n_tot - start; if (nodes > BINW) nodes = BINW;
    int t = threadIdx.x;
    int base = bin_base[b];
    int count = bin_base[b + 1] - base;
    const int* __restrict__ tb = temp + (size_t)b * BSLOT;
    // per-node histogram of this bin's payloads
    for (int i = t; i < BINW; i += 256) cur[i] = 0;
    __syncthreads();
    for (int i = t; i < count; i += 256)
        atomicAdd(&cur[(tb[i] >> 16) & (BINW - 1)], 1);
    __syncthreads();
    // exclusive scan of 512 counts (2 per thread + 256-wide Hillis-Steele)
    int a0 = cur[2 * t], a1 = cur[2 * t + 1];
    red[t] = a0 + a1;
    __syncthreads();
    for (int off = 1; off < 256; off <<= 1) {
        int u = (t >= off) ? red[t - off] : 0;
        __syncthreads();
        red[t] += u;
        __syncthreads();
    }
    int excl = red[t] - (a0 + a1);
    pfx[2 * t] = excl;
    pfx[2 * t + 1] = excl + a0;
    __syncthreads();
    // rowptr for this bin (boundary start+BINW written by the next bin; last bin: n_tot)
    for (int i = t; i < nodes; i += 256) rowptr[start + i] = base + pfx[i];
    if (b == nbins - 1 && t == 0) rowptr[n_tot] = base + count;
    // reset cursors to local starts
    for (int i = t; i < BINW; i += 256) cur[i] = pfx[i];
    __syncthreads();
    if (count <= BCAP) {
        for (int i = t; i < count; i += 256) {
            int v = tb[i];
            int p = atomicAdd(&cur[(v >> 16) & (BINW - 1)], 1);
            srt[p] = v & 0xFFFF;
        }
        __syncthreads();
        for (int i = t; i < count; i += 256) col[base + i] = srt[i];
    } else {  // fallback (not expected): direct global scatter
        for (int i = t; i < count; i += 256) {
            int v = tb[i];
            int p = atomicAdd(&cur[(v >> 16) & (BINW - 1)], 1);
            col[base + p] = v & 0xFFFF;
        }
    }
}

// ---------------- W pack: fp32 [k][n] -> MFMA B-fragment order, split bf16 hi/lo ----------------
// 15 matrices (5 per layer: Wl_isa, Wl_rev, Wsum=Wr_isa+Wr_rev, Wl_rel, Wr_rel).
// B-operand layout: n = ct*16 + (lane&15), k = kc*32 + (lane>>4)*8 + j.

struct WSrc { const float* a[15]; const float* b[15]; };

__global__ __launch_bounds__(256) void pack_w_kernel(WSrc src, short* __restrict__ whi,
                                                     short* __restrict__ wlo) {
    int idx = blockIdx.x * 256 + threadIdx.x;   // (mat, kc, ct, lane)
    if (idx >= 15 * 4 * 8 * 64) return;
    int lane = idx & 63;
    int ct = (idx >> 6) & 7;
    int kc = (idx >> 9) & 3;
    int mat = idx >> 11;
    const float* A = src.a[mat];
    const float* Bp = src.b[mat];
    int n = ct * 16 + (lane & 15);
    int kbase = kc * 32 + (lane >> 4) * 8;
    size_t o = (size_t)idx * 8;
    for (int j = 0; j < 8; ++j) {
        float v = A[(size_t)(kbase + j) * H + n];
        if (Bp) v += Bp[(size_t)(kbase + j) * H + n];
        short h = f2bf(v);
        whi[o + j] = h;
        wlo[o + j] = f2bf(v - bf2f(h));
    }
}

// ---------------- fp32 -> fp16 mirror convert (layer-0 inputs, both matrices) ----------------

__global__ __launch_bounds__(256) void cvt16_kernel(const float* __restrict__ xa, int n4a,
                                                    const float* __restrict__ xb, int n4b,
                                                    _Float16* __restrict__ ya,
                                                    _Float16* __restrict__ yb) {
    int i = blockIdx.x * 256 + threadIdx.x;
    const float* x; _Float16* y;
    if (i < n4a) { x = xa + (size_t)i * 4; y = ya + (size_t)i * 4; }
    else if (i < n4a + n4b) { x = xb + (size_t)(i - n4a) * 4; y = yb + (size_t)(i - n4a) * 4; }
    else return;
    f32x4 v = *(const f32x4*)x;
    half4v h;
#pragma unroll
    for (int k = 0; k < 4; ++k) h[k] = (_Float16)v[k];
    *(half4v*)y = h;
}

// ---------------- scalar-base fp16 segment mean (proven R3) ----------------
// Wave computes one dst row's mean; lane covers 2 features (voff = lane*2).
// readfirstlane forces the gathered row base into SGPR -> global_load saddr+voffset.
// 16-deep chunks; 16/8-wide masked tails (clamped dup index -> cache hit, weight 0).

__device__ __forceinline__ float2 seg16(const _Float16* __restrict__ x,
                                        const int* __restrict__ col,
                                        int beg, int end, int voff) {
    float ax0 = 0.f, ax1 = 0.f, ax2 = 0.f, ax3 = 0.f;
    float ay0 = 0.f, ay1 = 0.f, ay2 = 0.f, ay3 = 0.f;
    int e = beg;
    while (e + 16 <= end) {               // uniform loop control
        half2v v[16];
#pragma unroll
        for (int i = 0; i < 16; ++i) {
            int si = __builtin_amdgcn_readfirstlane(col[e + i]);   // SGPR row index
            v[i] = *(const half2v*)(x + (size_t)si * H + voff);    // saddr + voffset
        }
#pragma unroll
        for (int i = 0; i < 16; i += 4) {
            ax0 += (float)v[i + 0][0]; ay0 += (float)v[i + 0][1];
            ax1 += (float)v[i + 1][0]; ay1 += (float)v[i + 1][1];
            ax2 += (float)v[i + 2][0]; ay2 += (float)v[i + 2][1];
            ax3 += (float)v[i + 3][0]; ay3 += (float)v[i + 3][1];
        }
        e += 16;
    }
    int rem = end - e;
    if (rem > 8) {                        // 9..15 left: one 16-wide masked tail
        int last = end - 1;
        half2v v[16];
#pragma unroll
        for (int i = 0; i < 16; ++i) {
            int p = e + i; if (p > last) p = last;
            int si = __builtin_amdgcn_readfirstlane(col[p]);
            v[i] = *(const half2v*)(x + (size_t)si * H + voff);
        }
#pragma unroll
        for (int i = 0; i < 16; ++i) {
            float m = (i < rem) ? 1.0f : 0.0f;
            float fx = (float)v[i][0], fy = (float)v[i][1];
            if ((i & 3) == 0) { ax0 = fmaf(fx, m, ax0); ay0 = fmaf(fy, m, ay0); }
            else if ((i & 3) == 1) { ax1 = fmaf(fx, m, ax1); ay1 = fmaf(fy, m, ay1); }
            else if ((i & 3) == 2) { ax2 = fmaf(fx, m, ax2); ay2 = fmaf(fy, m, ay2); }
            else { ax3 = fmaf(fx, m, ax3); ay3 = fmaf(fy, m, ay3); }
        }
    } else if (rem > 0) {                 // 1..8 left: one 8-wide masked tail
        int last = end - 1;
        half2v v[8];
#pragma unroll
        for (int i = 0; i < 8; ++i) {
            int p = e + i; if (p > last) p = last;
            int si = __builtin_amdgcn_readfirstlane(col[p]);
            v[i] = *(const half2v*)(x + (size_t)si * H + voff);
        }
#pragma unroll
        for (int i = 0; i < 8; ++i) {
            float m = (i < rem) ? 1.0f : 0.0f;
            float fx = (float)v[i][0], fy = (float)v[i][1];
            if ((i & 3) == 0) { ax0 = fmaf(fx, m, ax0); ay0 = fmaf(fy, m, ay0); }
            else if ((i & 3) == 1) { ax1 = fmaf(fx, m, ax1); ay1 = fmaf(fy, m, ay1); }
            else if ((i & 3) == 2) { ax2 = fmaf(fx, m, ax2); ay2 = fmaf(fy, m, ay2); }
            else { ax3 = fmaf(fx, m, ax3); ay3 = fmaf(fy, m, ay3); }
        }
    }
    float sx = (ax0 + ax1) + (ax2 + ax3);
    float sy = (ay0 + ay1) + (ay2 + ay3);
    int c = end - beg; if (c < 1) c = 1;
    float inv = 1.0f / (float)c;
    return (float2){sx * inv, sy * inv};
}

// ---------------- fused SAGE layer: gather-mean -> LDS A-tile -> split-bf16 MFMA ----------------
// Each 64-row block builds its A-tile per term: gather terms compute per-row means
// directly into LDS (wave w owns rows 16w..16w+15; hi/lo split in-register -- operands
// bit-identical to the old M-materialized path), copy terms stream pre-split planes
// (or fp32 layer-0 inputs). Deletes the M write+read round-trip (150 MB/layer) and lets
// one block's gathers overlap another's MFMA.
// Epilogue: fp16 mirror (next layer's gathers / decoder) + split-bf16 planes (next
// layer's copy term; in-place on own rows only).

struct GTerm {
    const _Float16* x;   // gather source mirror (kind: gather if non-null)
    int rbase;           // rowptr base index for this edge type
    const short* hi;     // pre-split planes (kind: copy if non-null)
    const short* lo;
    const float* f;      // fp32 source (layer 0 copy)
};

template <int NIN>
__global__ __launch_bounds__(256, 3) void fused_gnn(
    GTerm t0, GTerm t1, GTerm t2,
    const int* __restrict__ rowptr, const int* __restrict__ col,
    const short* __restrict__ whi, const short* __restrict__ wlo,
    int mat0, int mat1, int mat2,
    const float* __restrict__ b0, const float* __restrict__ b1,
    _Float16* __restrict__ out16, short* __restrict__ ohi, short* __restrict__ olo,
    int n_rows, int relu) {
    __shared__ short Ahi[64 * RS];
    __shared__ short Alo[64 * RS];
    const int tid = threadIdx.x;
    const int lane = tid & 63;
    const int wave = __builtin_amdgcn_readfirstlane(tid >> 6);
    const int r0 = blockIdx.x * 64;
    const int ct0 = wave * 2;
    const int m16 = lane & 15;
    const int acol = (lane >> 4) * 8;

    f32x4 acc[4][2];
#pragma unroll
    for (int mt = 0; mt < 4; ++mt)
#pragma unroll
        for (int c = 0; c < 2; ++c) acc[mt][c] = (f32x4){0.f, 0.f, 0.f, 0.f};

    const GTerm terms[3] = {t0, t1, t2};
    const int marr[3] = {mat0, mat1, mat2};

#pragma unroll
    for (int m = 0; m < NIN; ++m) {
        const GTerm& T = terms[m];
        __syncthreads();
        if (T.x) {                          // gather-mean term: wave w owns rows 16w..16w+15
            int voff = lane * 2;
            for (int rr = 0; rr < 16; ++rr) {
                int lrow = wave * 16 + rr;
                int gr = r0 + lrow;
                if (gr >= n_rows) gr = n_rows - 1;     // dup row: harmless recompute
                int rb = T.rbase + gr;
                float2 s = seg16(T.x, col, rowptr[rb], rowptr[rb + 1], voff);
                short h0 = f2bf(s.x), h1 = f2bf(s.y);
                *(short2v*)&Ahi[lrow * RS + voff] = (short2v){h0, h1};
                *(short2v*)&Alo[lrow * RS + voff] =
                    (short2v){f2bf(s.x - bf2f(h0)), f2bf(s.y - bf2f(h1))};
            }
        } else if (T.hi) {                  // pre-split planes: pure copy
#pragma unroll
            for (int i = 0; i < 8; ++i) {
                int f = tid + i * 256;
                int row = f >> 5;
                int c4 = (f & 31) * 4;
                int gr = r0 + row;
                if (gr >= n_rows) gr = n_rows - 1;
                size_t o = (size_t)gr * H + c4;
                *(short4v*)&Ahi[row * RS + c4] = *(const short4v*)&T.hi[o];
                *(short4v*)&Alo[row * RS + c4] = *(const short4v*)&T.lo[o];
            }
        } else {                            // fp32 (layer 0): split on stage
            const float* __restrict__ A = T.f;
#pragma unroll
            for (int i = 0; i < 8; ++i) {
                int f = tid + i * 256;
                int row = f >> 5;
                int c4 = (f & 31) * 4;
                int gr = r0 + row;
                if (gr >= n_rows) gr = n_rows - 1;
                float4 v = *(const float4*)&A[(size_t)gr * H + c4];
                short h0 = f2bf(v.x), h1 = f2bf(v.y), h2 = f2bf(v.z), h3 = f2bf(v.w);
                *(short4v*)&Ahi[row * RS + c4] = (short4v){h0, h1, h2, h3};
                *(short4v*)&Alo[row * RS + c4] =
                    (short4v){f2bf(v.x - bf2f(h0)), f2bf(v.y - bf2f(h1)),
                              f2bf(v.z - bf2f(h2)), f2bf(v.w - bf2f(h3))};
            }
        }
        __syncthreads();
        const short* __restrict__ wh = whi + (size_t)marr[m] * (H * H);
        const short* __restrict__ wl = wlo + (size_t)marr[m] * (H * H);
        short8 bh[2][2], bl[2][2];
        {
            size_t f0 = ((size_t)ct0 * 64 + lane) * 8;
            bh[0][0] = *(const short8*)&wh[f0];
            bh[0][1] = *(const short8*)&wh[f0 + 512];
            bl[0][0] = *(const short8*)&wl[f0];
            bl[0][1] = *(const short8*)&wl[f0 + 512];
        }
#pragma unroll
        for (int kc = 0; kc < 4; ++kc) {
            if (kc < 3) {
                int nb = (kc + 1) & 1;
                size_t f = ((size_t)((kc + 1) * 8 + ct0) * 64 + lane) * 8;
                bh[nb][0] = *(const short8*)&wh[f];
                bh[nb][1] = *(const short8*)&wh[f + 512];
                bl[nb][0] = *(const short8*)&wl[f];
                bl[nb][1] = *(const short8*)&wl[f + 512];
            }
            int cb = kc & 1;
#pragma unroll
            for (int mt = 0; mt < 4; ++mt) {
                short8 ah = *(const short8*)&Ahi[(mt * 16 + m16) * RS + kc * 32 + acol];
                short8 al = *(const short8*)&Alo[(mt * 16 + m16) * RS + kc * 32 + acol];
#pragma unroll
                for (int c = 0; c < 2; ++c) {
                    acc[mt][c] = __builtin_amdgcn_mfma_f32_16x16x32_bf16(ah, bh[cb][c], acc[mt][c], 0, 0, 0);
                    acc[mt][c] = __builtin_amdgcn_mfma_f32_16x16x32_bf16(al, bh[cb][c], acc[mt][c], 0, 0, 0);
                    acc[mt][c] = __builtin_amdgcn_mfma_f32_16x16x32_bf16(ah, bl[cb][c], acc[mt][c], 0, 0, 0);
                }
            }
        }
    }

    const int rquad = (lane >> 4) * 4;
    const int ncol = lane & 15;
#pragma unroll
    for (int c = 0; c < 2; ++c) {
        int n = (ct0 + c) * 16 + ncol;
        float bs = b0[n];
        if (b1) bs += b1[n];
#pragma unroll
        for (int mt = 0; mt < 4; ++mt) {
#pragma unroll
            for (int reg = 0; reg < 4; ++reg) {
                int gr = r0 + mt * 16 + rquad + reg;
                if (gr < n_rows) {
                    float v = acc[mt][c][reg] + bs;
                    if (relu) v = v > 0.f ? v : 0.01f * v;
                    size_t o = (size_t)gr * H + n;
                    out16[o] = (_Float16)v;
                    short h = f2bf(v);
                    ohi[o] = h;
                    olo[o] = f2bf(v - bf2f(h));
                }
            }
        }
    }
}

// ---------------- edge decoder: sigmoid(dot(xp[i], xg[j])) on fp16 mirrors ----------------

__global__ __launch_bounds__(256) void scores_kernel(const _Float16* __restrict__ xp,
                                                     const _Float16* __restrict__ xg,
                                                     const int* __restrict__ eli, int E,
                                                     float* __restrict__ out) {
    int lane16 = threadIdx.x & 15;
    int sub = threadIdx.x >> 4;     // 16 edges per block
    int e = blockIdx.x * 16 + sub;
    if (e >= E) return;
    int ip = eli[e];
    int ig = eli[E + e];
    half8v a = *(const half8v*)&xp[(size_t)ip * H + lane16 * 8];
    half8v b = *(const half8v*)&xg[(size_t)ig * H + lane16 * 8];
    float s = 0.f;
#pragma unroll
    for (int k = 0; k < 8; ++k) s += (float)a[k] * (float)b[k];
#pragma unroll
    for (int off = 8; off; off >>= 1) s += __shfl_xor(s, off, 16);
    if (lane16 == 0) out[e] = 1.0f / (1.0f + expf(-s));
}

// ---------------- host ----------------

extern "C" void kernel_launch(void* const* d_in, const int* in_sizes, int n_in,
                              void* d_out, int out_size, void* d_ws, size_t ws_size,
                              hipStream_t stream) {
    const float* x_pheno = (const float*)d_in[0];
    const float* x_gene  = (const float*)d_in[1];
    const float* Wl_isa  = (const float*)d_in[2];
    const float* bl_isa  = (const float*)d_in[3];
    const float* Wr_isa  = (const float*)d_in[4];
    const float* Wl_rel  = (const float*)d_in[5];
    const float* bl_rel  = (const float*)d_in[6];
    const float* Wr_rel  = (const float*)d_in[7];
    const float* Wl_rev  = (const float*)d_in[8];
    const float* bl_rev  = (const float*)d_in[9];
    const float* Wr_rev  = (const float*)d_in[10];
    const int* e_isa = (const int*)d_in[11];
    const int* e_rel = (const int*)d_in[12];
    const int* e_rev = (const int*)d_in[13];
    const int* e_lbl = (const int*)d_in[14];
    const int E_isa = in_sizes[11] / 2;
    const int E_rel = in_sizes[12] / 2;
    const int E_rev = in_sizes[13] / 2;
    const int E_lbl = in_sizes[14] / 2;
    const int NP = in_sizes[0] / H;
    const int NG = in_sizes[1] / H;
    const int n_tot = NP + NG + NP;
    const int E_tot = E_isa + E_rel + E_rev;
    const int nbins = (n_tot + BINW - 1) / BINW;

    char* ws = (char*)d_ws;
    auto alloc = [&](size_t bytes) -> char* {
        char* p = ws;
        ws += (bytes + 255) & ~(size_t)255;
        return p;
    };
    int* rowptr  = (int*)alloc((size_t)(n_tot + 1) * 4);
    int* col     = (int*)alloc((size_t)E_tot * 4);
    int* temp    = (int*)alloc((size_t)nbins * BSLOT * 4);
    int* bin_cur = (int*)alloc((size_t)nbins * 16 * 4);   // 64B-strided counters
    int* bin_base= (int*)alloc((size_t)(nbins + 1) * 4);
    short* whi = (short*)alloc((size_t)15 * H * H * sizeof(short));
    short* wlo = (short*)alloc((size_t)15 * H * H * sizeof(short));
    _Float16* xpm[2], *xgm[2];
    xpm[0] = (_Float16*)alloc((size_t)NP * H * sizeof(_Float16));
    xpm[1] = (_Float16*)alloc((size_t)NP * H * sizeof(_Float16));
    xgm[0] = (_Float16*)alloc((size_t)NG * H * sizeof(_Float16));
    xgm[1] = (_Float16*)alloc((size_t)NG * H * sizeof(_Float16));
    short* xph = (short*)alloc((size_t)NP * H * sizeof(short));
    short* xpl = (short*)alloc((size_t)NP * H * sizeof(short));
    short* xgh = (short*)alloc((size_t)NG * H * sizeof(short));
    short* xgl = (short*)alloc((size_t)NG * H * sizeof(short));

    // ---- CSR build (every call; ws is re-poisoned by the harness) ----
    hipMemsetAsync(bin_cur, 0, (size_t)nbins * 16 * 4, stream);
    bin_scatter_kernel<<<(E_tot + KEDGE - 1) / KEDGE, 256, 0, stream>>>(
        e_isa, E_isa, e_rel, E_rel, e_rev, E_rev, bin_cur, temp, NP, NG, nbins, E_tot);
    scan_bins<<<1, 1024, 0, stream>>>(bin_cur, nbins, bin_base);
    bin_sort_kernel<<<nbins, 256, 0, stream>>>(bin_base, temp, col, rowptr, n_tot, nbins);

    // ---- W pack: per layer slots {Wl_isa, Wl_rev, Wsum=Wr_isa+Wr_rev, Wl_rel, Wr_rel} ----
    WSrc src;
    for (int l = 0; l < 3; ++l) {
        src.a[l * 5 + 0] = Wl_isa + (size_t)l * H * H;  src.b[l * 5 + 0] = nullptr;
        src.a[l * 5 + 1] = Wl_rev + (size_t)l * H * H;  src.b[l * 5 + 1] = nullptr;
        src.a[l * 5 + 2] = Wr_isa + (size_t)l * H * H;  src.b[l * 5 + 2] = Wr_rev + (size_t)l * H * H;
        src.a[l * 5 + 3] = Wl_rel + (size_t)l * H * H;  src.b[l * 5 + 3] = nullptr;
        src.a[l * 5 + 4] = Wr_rel + (size_t)l * H * H;  src.b[l * 5 + 4] = nullptr;
    }
    pack_w_kernel<<<(15 * 4 * 8 * 64 + 255) / 256, 256, 0, stream>>>(src, whi, wlo);

    // ---- layer-0 fp16 mirrors of the inputs (set 0) ----
    cvt16_kernel<<<((NP + NG) * 32 + 255) / 256, 256, 0, stream>>>(
        x_pheno, NP * 32, x_gene, NG * 32, xpm[0], xgm[0]);

    // ---- 3 fused layers ----
    // Mirrors ping-pong (read set rs = l&1, write set rs^1) so NG-fused can read old
    // xp16 after NP-fused ran. Planes are single-buffered: each kernel reads its own
    // rows before the epilogue overwrites them (block-local, proven pattern).
    const short *pph = nullptr, *ppl = nullptr, *pgh = nullptr, *pgl = nullptr;
    for (int l = 0; l < 3; ++l) {
        int rs = l & 1;
        int wsid = rs ^ 1;
        int relu = (l < 2) ? 1 : 0;
        const float* bli = bl_isa + (size_t)l * H;
        const float* blv = bl_rev + (size_t)l * H;
        const float* blr = bl_rel + (size_t)l * H;
        // new_p = isa-mean(xp)@Wl_isa + rev-mean(xg)@Wl_rev + xp@(Wr_isa+Wr_rev) + biases
        GTerm isa{xpm[rs], 0, nullptr, nullptr, nullptr};
        GTerm rev{xgm[rs], NP + NG, nullptr, nullptr, nullptr};
        GTerm xpt{nullptr, 0, pph, ppl, l == 0 ? x_pheno : nullptr};
        fused_gnn<3><<<(NP + 63) / 64, 256, 0, stream>>>(
            isa, rev, xpt, rowptr, col, whi, wlo, l * 5 + 0, l * 5 + 1, l * 5 + 2,
            bli, blv, xpm[wsid], xph, xpl, NP, relu);
        // new_g = rel-mean(xp)@Wl_rel + xg@Wr_rel + bl_rel
        GTerm rel{xpm[rs], NP, nullptr, nullptr, nullptr};
        GTerm xgt{nullptr, 0, pgh, pgl, l == 0 ? x_gene : nullptr};
        GTerm nil{nullptr, 0, nullptr, nullptr, nullptr};
        fused_gnn<2><<<(NG + 63) / 64, 256, 0, stream>>>(
            rel, xgt, nil, rowptr, col, whi, wlo, l * 5 + 3, l * 5 + 4, 0,
            blr, nullptr, xgm[wsid], xgh, xgl, NG, relu);
        pph = xph; ppl = xpl; pgh = xgh; pgl = xgl;
    }

    // ---- decoder (layer 2 wrote mirror set 1) ----
    scores_kernel<<<(E_lbl + 15) / 16, 256, 0, stream>>>(xpm[1], xgm[1], e_lbl, E_lbl,
                                                         (float*)d_out);
}